// Round 1
// baseline (6943.522 us; speedup 1.0000x reference)
//
#include <hip/hip_runtime.h>
#include <hip/hip_bf16.h>

// ---------------------------------------------------------------------------
// GCN 3-layer forward. N=100000, E=1600000, F: 64 -> 128 -> 128 -> 64.
// Pipeline per call:
//   deg (self-loop=1 + atomic count) -> dinv=rsqrt(deg) -> norm[e]=dinv[s]*dinv[d]
//   3x: GEMM (LDS-tiled f32, ReLU fused on A-load for layers 2/3)
//       init_agg = b + dinv^2 * hw   (self-loop folded, full overwrite)
//       scatter: atomicAdd(agg[dst], hw[src]*norm)
// ---------------------------------------------------------------------------

__global__ __launch_bounds__(256) void init_deg_k(float* deg, int n) {
    int i = blockIdx.x * 256 + threadIdx.x;
    if (i < n) deg[i] = 1.0f;  // self-loop
}

__global__ __launch_bounds__(256) void count_deg_k(const int* __restrict__ dst,
                                                   float* deg, int E) {
    int e = blockIdx.x * 256 + threadIdx.x;
    if (e < E) atomicAdd(&deg[dst[e]], 1.0f);
}

__global__ __launch_bounds__(256) void dinv_k(float* deg, int n) {
    int i = blockIdx.x * 256 + threadIdx.x;
    if (i < n) deg[i] = rsqrtf(deg[i]);  // deg >= 1 always
}

__global__ __launch_bounds__(256) void norm_k(const int* __restrict__ src,
                                              const int* __restrict__ dst,
                                              const float* __restrict__ dinv,
                                              float* __restrict__ norm, int E) {
    int e = blockIdx.x * 256 + threadIdx.x;
    if (e < E) norm[e] = dinv[src[e]] * dinv[dst[e]];
}

// C[n,FOUT] = (RELU? max(A,0) : A)[n,K] @ W[K,FOUT]
// 64 rows per block, 256 threads. A tile staged in LDS; W via L1 (<=64KB).
constexpr int BR = 64;
template <int K, int FOUT, bool RELU>
__global__ __launch_bounds__(256) void gemm_k(const float* __restrict__ A,
                                              const float* __restrict__ W,
                                              float* __restrict__ C, int n) {
    constexpr int TPC = FOUT / 4;        // threads across columns
    constexpr int RPT = BR * TPC / 256;  // rows per thread
    __shared__ float As[BR][K + 4];
    int tid = threadIdx.x;
    int row0 = blockIdx.x * BR;

    for (int i = tid * 4; i < BR * K; i += 1024) {
        int r = i / K, k = i % K;
        int row = row0 + r;
        float4 v = make_float4(0.f, 0.f, 0.f, 0.f);
        if (row < n) v = *(const float4*)(A + (long)row * K + k);
        if (RELU) {
            v.x = fmaxf(v.x, 0.f); v.y = fmaxf(v.y, 0.f);
            v.z = fmaxf(v.z, 0.f); v.w = fmaxf(v.w, 0.f);
        }
        *(float4*)&As[r][k] = v;
    }
    __syncthreads();

    int tx = tid % TPC, ty = tid / TPC;
    float4 acc[RPT];
#pragma unroll
    for (int i = 0; i < RPT; i++) acc[i] = make_float4(0.f, 0.f, 0.f, 0.f);

    for (int k = 0; k < K; k += 4) {
        float4 w0 = *(const float4*)(W + (k + 0) * FOUT + tx * 4);
        float4 w1 = *(const float4*)(W + (k + 1) * FOUT + tx * 4);
        float4 w2 = *(const float4*)(W + (k + 2) * FOUT + tx * 4);
        float4 w3 = *(const float4*)(W + (k + 3) * FOUT + tx * 4);
#pragma unroll
        for (int i = 0; i < RPT; i++) {
            int r = ty * RPT + i;
            float4 a = *(float4*)&As[r][k];
            acc[i].x += a.x * w0.x + a.y * w1.x + a.z * w2.x + a.w * w3.x;
            acc[i].y += a.x * w0.y + a.y * w1.y + a.z * w2.y + a.w * w3.y;
            acc[i].z += a.x * w0.z + a.y * w1.z + a.z * w2.z + a.w * w3.z;
            acc[i].w += a.x * w0.w + a.y * w1.w + a.z * w2.w + a.w * w3.w;
        }
    }
#pragma unroll
    for (int i = 0; i < RPT; i++) {
        int row = row0 + ty * RPT + i;
        if (row < n) *(float4*)(C + (long)row * FOUT + tx * 4) = acc[i];
    }
}

// agg = b + dinv^2 * hw   (full overwrite; self-loop contribution folded in)
template <int F>
__global__ __launch_bounds__(256) void init_agg_k(const float* __restrict__ hw,
                                                  const float* __restrict__ dinv,
                                                  const float* __restrict__ b,
                                                  float* __restrict__ agg, int n) {
    constexpr int F4 = F / 4;
    int t = blockIdx.x * 256 + threadIdx.x;
    if (t >= n * F4) return;
    int node = t / F4, q = t % F4;
    float di = dinv[node];
    float s = di * di;
    float4 v = *(const float4*)(hw + (long)t * 4);
    float4 bb = *(const float4*)(b + q * 4);
    float4 o;
    o.x = bb.x + v.x * s; o.y = bb.y + v.y * s;
    o.z = bb.z + v.z * s; o.w = bb.w + v.w * s;
    *(float4*)(agg + (long)t * 4) = o;
}

// one thread per (edge, 4 features)
template <int F>
__global__ __launch_bounds__(256) void scatter_k(const float* __restrict__ hw,
                                                 const int* __restrict__ src,
                                                 const int* __restrict__ dst,
                                                 const float* __restrict__ norm,
                                                 float* __restrict__ agg, int E) {
    constexpr int F4 = F / 4;
    int t = blockIdx.x * 256 + threadIdx.x;
    if (t >= E * F4) return;
    int e = t / F4, q = t % F4;
    int s = src[e], d = dst[e];
    float nr = norm[e];
    float4 v = *(const float4*)(hw + (long)s * F + q * 4);
    float* p = agg + (long)d * F + q * 4;
    atomicAdd(p + 0, v.x * nr);
    atomicAdd(p + 1, v.y * nr);
    atomicAdd(p + 2, v.z * nr);
    atomicAdd(p + 3, v.w * nr);
}

extern "C" void kernel_launch(void* const* d_in, const int* in_sizes, int n_in,
                              void* d_out, int out_size, void* d_ws, size_t ws_size,
                              hipStream_t stream) {
    const float* x  = (const float*)d_in[0];
    const int*   ei = (const int*)d_in[1];
    const float* W1 = (const float*)d_in[2];
    const float* b1 = (const float*)d_in[3];
    const float* W2 = (const float*)d_in[4];
    const float* b2 = (const float*)d_in[5];
    const float* W3 = (const float*)d_in[6];
    const float* b3 = (const float*)d_in[7];
    float* out = (float*)d_out;

    const int N = in_sizes[0] / 64;
    const int E = in_sizes[1] / 2;
    const int* src = ei;
    const int* dst = ei + E;

    float* deg  = (float*)d_ws;          // N floats; becomes dinv in place
    float* nrm  = deg + N;               // E floats
    float* bufA = nrm + E;               // N*128 floats (hw)
    float* bufB = bufA + (long)N * 128;  // N*128 floats (agg ping)

    const int nb  = (N + 255) / 256;
    const int eb  = (E + 255) / 256;
    const int gb  = (N + BR - 1) / BR;

    init_deg_k<<<nb, 256, 0, stream>>>(deg, N);
    count_deg_k<<<eb, 256, 0, stream>>>(dst, deg, E);
    dinv_k<<<nb, 256, 0, stream>>>(deg, N);
    norm_k<<<eb, 256, 0, stream>>>(src, dst, deg, nrm, E);

    // ---- layer 1: x[N,64] @ W1[64,128] ----
    gemm_k<64, 128, false><<<gb, 256, 0, stream>>>(x, W1, bufA, N);
    init_agg_k<128><<<(N * 32 + 255) / 256, 256, 0, stream>>>(bufA, deg, b1, bufB, N);
    scatter_k<128><<<(E * 32 + 255) / 256, 256, 0, stream>>>(bufA, src, dst, nrm, bufB, E);

    // ---- layer 2: relu(h)[N,128] @ W2[128,128] ----
    gemm_k<128, 128, true><<<gb, 256, 0, stream>>>(bufB, W2, bufA, N);
    init_agg_k<128><<<(N * 32 + 255) / 256, 256, 0, stream>>>(bufA, deg, b2, bufB, N);
    scatter_k<128><<<(E * 32 + 255) / 256, 256, 0, stream>>>(bufA, src, dst, nrm, bufB, E);

    // ---- layer 3: relu(h)[N,128] @ W3[128,64] -> d_out ----
    gemm_k<128, 64, true><<<gb, 256, 0, stream>>>(bufB, W3, bufA, N);
    init_agg_k<64><<<(N * 16 + 255) / 256, 256, 0, stream>>>(bufA, deg, b3, out, N);
    scatter_k<64><<<(E * 16 + 255) / 256, 256, 0, stream>>>(bufA, src, dst, nrm, out, E);
}

// Round 2
// 718.648 us; speedup vs baseline: 9.6619x; 9.6619x over previous
//
#include <hip/hip_runtime.h>
#include <hip/hip_bf16.h>

// ---------------------------------------------------------------------------
// GCN 3-layer forward. N=100000, E=1600000, F: 64 -> 128 -> 128 -> 64.
// R2: scatter-atomics -> CSR-by-dst + per-node register-accumulated gather.
//   cnt[dst]++  ->  exclusive scan (2-level)  ->  fill col[] via atomic cursor
//   dinv = rsqrt(cnt+1)
//   3x: GEMM (LDS-tiled f32, fused ReLU on A-load)
//       agg[n] = b + dinv[n]^2*hw[n] + sum_e dinv[col[e]]*dinv[n]*hw[col[e]]
// ---------------------------------------------------------------------------

__global__ __launch_bounds__(256) void zero_int_k(int* p, int n) {
    int i = blockIdx.x * 256 + threadIdx.x;
    if (i < n) p[i] = 0;
}

__global__ __launch_bounds__(256) void count_k(const int* __restrict__ dst,
                                               int* __restrict__ cnt, int E) {
    int e = blockIdx.x * 256 + threadIdx.x;
    if (e < E) atomicAdd(&cnt[dst[e]], 1);
}

// inclusive block scan (256 elems/block) -> exclusive per-element + block sums
__global__ __launch_bounds__(256) void scan_blocks_k(const int* __restrict__ cnt,
                                                     int* __restrict__ excl,
                                                     int* __restrict__ bsums, int n) {
    __shared__ int s[256];
    int tid = threadIdx.x;
    int i = blockIdx.x * 256 + tid;
    int v = (i < n) ? cnt[i] : 0;
    s[tid] = v;
    __syncthreads();
    for (int off = 1; off < 256; off <<= 1) {
        int t = (tid >= off) ? s[tid - off] : 0;
        __syncthreads();
        s[tid] += t;
        __syncthreads();
    }
    if (i < n) excl[i] = s[tid] - v;
    if (tid == 255) bsums[blockIdx.x] = s[255];
}

// single-block exclusive scan of block sums (nb <= 512)
__global__ __launch_bounds__(512) void scan_sums_k(int* bsums, int nb) {
    __shared__ int s[512];
    int tid = threadIdx.x;
    int v = (tid < nb) ? bsums[tid] : 0;
    s[tid] = v;
    __syncthreads();
    for (int off = 1; off < 512; off <<= 1) {
        int t = (tid >= off) ? s[tid - off] : 0;
        __syncthreads();
        s[tid] += t;
        __syncthreads();
    }
    if (tid < nb) bsums[tid] = s[tid] - v;  // exclusive
}

// row_start (in-place on excl) += block offset; cursor = row_start; dinv
__global__ __launch_bounds__(256) void finish_scan_k(int* __restrict__ rowst,
                                                     int* __restrict__ cursor,
                                                     const int* __restrict__ bsums,
                                                     const int* __restrict__ cnt,
                                                     float* __restrict__ dinv, int n) {
    int i = blockIdx.x * 256 + threadIdx.x;
    if (i >= n) return;
    int r = rowst[i] + bsums[blockIdx.x];
    rowst[i] = r;
    cursor[i] = r;
    dinv[i] = rsqrtf((float)cnt[i] + 1.0f);
}

__global__ __launch_bounds__(256) void fill_k(const int* __restrict__ src,
                                              const int* __restrict__ dst,
                                              int* __restrict__ cursor,
                                              int* __restrict__ col, int E) {
    int e = blockIdx.x * 256 + threadIdx.x;
    if (e >= E) return;
    int pos = atomicAdd(&cursor[dst[e]], 1);
    col[pos] = src[e];
}

// C[n,FOUT] = (RELU? max(A,0) : A)[n,K] @ W[K,FOUT]
constexpr int BR = 64;
template <int K, int FOUT, bool RELU>
__global__ __launch_bounds__(256) void gemm_k(const float* __restrict__ A,
                                              const float* __restrict__ W,
                                              float* __restrict__ C, int n) {
    constexpr int TPC = FOUT / 4;
    constexpr int RPT = BR * TPC / 256;
    __shared__ float As[BR][K + 4];
    int tid = threadIdx.x;
    int row0 = blockIdx.x * BR;

    for (int i = tid * 4; i < BR * K; i += 1024) {
        int r = i / K, k = i % K;
        int row = row0 + r;
        float4 v = make_float4(0.f, 0.f, 0.f, 0.f);
        if (row < n) v = *(const float4*)(A + (long)row * K + k);
        if (RELU) {
            v.x = fmaxf(v.x, 0.f); v.y = fmaxf(v.y, 0.f);
            v.z = fmaxf(v.z, 0.f); v.w = fmaxf(v.w, 0.f);
        }
        *(float4*)&As[r][k] = v;
    }
    __syncthreads();

    int tx = tid % TPC, ty = tid / TPC;
    float4 acc[RPT];
#pragma unroll
    for (int i = 0; i < RPT; i++) acc[i] = make_float4(0.f, 0.f, 0.f, 0.f);

    for (int k = 0; k < K; k += 4) {
        float4 w0 = *(const float4*)(W + (k + 0) * FOUT + tx * 4);
        float4 w1 = *(const float4*)(W + (k + 1) * FOUT + tx * 4);
        float4 w2 = *(const float4*)(W + (k + 2) * FOUT + tx * 4);
        float4 w3 = *(const float4*)(W + (k + 3) * FOUT + tx * 4);
#pragma unroll
        for (int i = 0; i < RPT; i++) {
            int r = ty * RPT + i;
            float4 a = *(float4*)&As[r][k];
            acc[i].x += a.x * w0.x + a.y * w1.x + a.z * w2.x + a.w * w3.x;
            acc[i].y += a.x * w0.y + a.y * w1.y + a.z * w2.y + a.w * w3.y;
            acc[i].z += a.x * w0.z + a.y * w1.z + a.z * w2.z + a.w * w3.z;
            acc[i].w += a.x * w0.w + a.y * w1.w + a.z * w2.w + a.w * w3.w;
        }
    }
#pragma unroll
    for (int i = 0; i < RPT; i++) {
        int row = row0 + ty * RPT + i;
        if (row < n) *(float4*)(C + (long)row * FOUT + tx * 4) = acc[i];
    }
}

// Per-dst-node gather-aggregate: F4 lanes per node, register accumulation.
// agg[n,:] = b + dinv[n]^2*hw[n,:] + sum_{e in [beg,end)} dinv[col[e]]*dinv[n]*hw[col[e],:]
template <int F>
__global__ __launch_bounds__(256) void agg_k(const float* __restrict__ hw,
                                             const int* __restrict__ rowst,
                                             const int* __restrict__ rowend,
                                             const int* __restrict__ col,
                                             const float* __restrict__ dinv,
                                             const float* __restrict__ b,
                                             float* __restrict__ agg, int n) {
    constexpr int F4 = F / 4;
    constexpr int NPB = 256 / F4;
    int node = blockIdx.x * NPB + threadIdx.x / F4;
    int q = threadIdx.x % F4;
    if (node >= n) return;

    float di = dinv[node];
    float4 bb = *(const float4*)(b + q * 4);
    float4 self = *(const float4*)(hw + (long)node * F + q * 4);
    float s2 = di * di;
    float4 acc;
    acc.x = bb.x + self.x * s2;
    acc.y = bb.y + self.y * s2;
    acc.z = bb.z + self.z * s2;
    acc.w = bb.w + self.w * s2;

    int beg = rowst[node], end = rowend[node];
    for (int e = beg; e < end; e++) {
        int s = col[e];
        float nr = dinv[s] * di;
        float4 v = *(const float4*)(hw + (long)s * F + q * 4);
        acc.x += v.x * nr;
        acc.y += v.y * nr;
        acc.z += v.z * nr;
        acc.w += v.w * nr;
    }
    *(float4*)(agg + (long)node * F + q * 4) = acc;
}

extern "C" void kernel_launch(void* const* d_in, const int* in_sizes, int n_in,
                              void* d_out, int out_size, void* d_ws, size_t ws_size,
                              hipStream_t stream) {
    const float* x  = (const float*)d_in[0];
    const int*   ei = (const int*)d_in[1];
    const float* W1 = (const float*)d_in[2];
    const float* b1 = (const float*)d_in[3];
    const float* W2 = (const float*)d_in[4];
    const float* b2 = (const float*)d_in[5];
    const float* W3 = (const float*)d_in[6];
    const float* b3 = (const float*)d_in[7];
    float* out = (float*)d_out;

    const int N = in_sizes[0] / 64;
    const int E = in_sizes[1] / 2;
    const int* src = ei;
    const int* dst = ei + E;

    // workspace carve-up (all 4-byte elems)
    int*   cnt    = (int*)d_ws;              // N
    int*   rowst  = cnt + N;                 // N (excl scan in place)
    int*   cursor = rowst + N;               // N (becomes row end after fill)
    int*   bsums  = cursor + N;              // 1024
    float* dinv   = (float*)(bsums + 1024);  // N
    int*   col    = (int*)(dinv + N);        // E
    float* bufA   = (float*)(col + E);       // N*128
    float* bufB   = bufA + (long)N * 128;    // N*128

    const int nb = (N + 255) / 256;
    const int eb = (E + 255) / 256;
    const int gb = (N + BR - 1) / BR;

    // ---- CSR build + norms ----
    zero_int_k<<<nb, 256, 0, stream>>>(cnt, N);
    count_k<<<eb, 256, 0, stream>>>(dst, cnt, E);
    scan_blocks_k<<<nb, 256, 0, stream>>>(cnt, rowst, bsums, N);
    scan_sums_k<<<1, 512, 0, stream>>>(bsums, nb);
    finish_scan_k<<<nb, 256, 0, stream>>>(rowst, cursor, bsums, cnt, dinv, N);
    fill_k<<<eb, 256, 0, stream>>>(src, dst, cursor, col, E);

    // ---- layer 1: x[N,64] @ W1[64,128] ----
    gemm_k<64, 128, false><<<gb, 256, 0, stream>>>(x, W1, bufA, N);
    agg_k<128><<<(N * 32 + 255) / 256, 256, 0, stream>>>(bufA, rowst, cursor, col,
                                                         dinv, b1, bufB, N);

    // ---- layer 2: relu(h)[N,128] @ W2[128,128] ----
    gemm_k<128, 128, true><<<gb, 256, 0, stream>>>(bufB, W2, bufA, N);
    agg_k<128><<<(N * 32 + 255) / 256, 256, 0, stream>>>(bufA, rowst, cursor, col,
                                                         dinv, b2, bufB, N);

    // ---- layer 3: relu(h)[N,128] @ W3[128,64] -> d_out ----
    gemm_k<128, 64, true><<<gb, 256, 0, stream>>>(bufB, W3, bufA, N);
    agg_k<64><<<(N * 16 + 255) / 256, 256, 0, stream>>>(bufA, rowst, cursor, col,
                                                        dinv, b3, out, N);
}

// Round 3
// 562.217 us; speedup vs baseline: 12.3503x; 1.2782x over previous
//
#include <hip/hip_runtime.h>
#include <hip/hip_bf16.h>
#include <hip/hip_fp16.h>

// ---------------------------------------------------------------------------
// GCN 3-layer forward. N=100000, E=1600000, F: 64 -> 128 -> 128 -> 64.
// R3: f16 message tables (dinv pre-folded) + aggregate-transform commute.
//   CSR by dst (count -> scan -> fill), dinv = rsqrt(deg+1)
//   msgX  = dinv (.) x                  (f16, N x 64)
//   aggX  = dinv * (msgX[n] + S msgX[col])            (f32)
//   msg1  = dinv (.) relu(aggX @ W1 + b1)             (f16, gemm1 epilogue)
//   aggH1 = dinv * (msg1[n] + S msg1[col])            (f32)
//   h2    = relu(aggH1 @ W2 + b2)                     (f32, gemm2)
//   msg3  = dinv (.) (h2 @ W3)                        (f16, gemm3 epilogue)
//   out   = b3 + dinv * (msg3[n] + S msg3[col])       (f32)
// ---------------------------------------------------------------------------

__global__ __launch_bounds__(256) void zero_int_k(int* p, int n) {
    int i = blockIdx.x * 256 + threadIdx.x;
    if (i < n) p[i] = 0;
}

__global__ __launch_bounds__(256) void count_k(const int* __restrict__ dst,
                                               int* __restrict__ cnt, int E) {
    int e = blockIdx.x * 256 + threadIdx.x;
    if (e < E) atomicAdd(&cnt[dst[e]], 1);
}

__global__ __launch_bounds__(256) void scan_blocks_k(const int* __restrict__ cnt,
                                                     int* __restrict__ excl,
                                                     int* __restrict__ bsums, int n) {
    __shared__ int s[256];
    int tid = threadIdx.x;
    int i = blockIdx.x * 256 + tid;
    int v = (i < n) ? cnt[i] : 0;
    s[tid] = v;
    __syncthreads();
    for (int off = 1; off < 256; off <<= 1) {
        int t = (tid >= off) ? s[tid - off] : 0;
        __syncthreads();
        s[tid] += t;
        __syncthreads();
    }
    if (i < n) excl[i] = s[tid] - v;
    if (tid == 255) bsums[blockIdx.x] = s[255];
}

__global__ __launch_bounds__(512) void scan_sums_k(int* bsums, int nb) {
    __shared__ int s[512];
    int tid = threadIdx.x;
    int v = (tid < nb) ? bsums[tid] : 0;
    s[tid] = v;
    __syncthreads();
    for (int off = 1; off < 512; off <<= 1) {
        int t = (tid >= off) ? s[tid - off] : 0;
        __syncthreads();
        s[tid] += t;
        __syncthreads();
    }
    if (tid < nb) bsums[tid] = s[tid] - v;  // exclusive
}

__global__ __launch_bounds__(256) void finish_scan_k(int* __restrict__ rowst,
                                                     int* __restrict__ cursor,
                                                     const int* __restrict__ bsums,
                                                     const int* __restrict__ cnt,
                                                     float* __restrict__ dinv, int n) {
    int i = blockIdx.x * 256 + threadIdx.x;
    if (i >= n) return;
    int r = rowst[i] + bsums[blockIdx.x];
    rowst[i] = r;
    cursor[i] = r;
    dinv[i] = rsqrtf((float)cnt[i] + 1.0f);
}

__global__ __launch_bounds__(256) void fill_k(const int* __restrict__ src,
                                              const int* __restrict__ dst,
                                              int* __restrict__ cursor,
                                              int* __restrict__ col, int E) {
    int e = blockIdx.x * 256 + threadIdx.x;
    if (e >= E) return;
    int pos = atomicAdd(&cursor[dst[e]], 1);
    col[pos] = src[e];
}

// ---- f16 helpers ----------------------------------------------------------
__device__ inline void load8h(const __half* p, float* f) {
    uint4 raw = *(const uint4*)p;  // 16B = 8 halves
    const __half2* h = (const __half2*)&raw;
    float2 a = __half22float2(h[0]);
    float2 b = __half22float2(h[1]);
    float2 c = __half22float2(h[2]);
    float2 d = __half22float2(h[3]);
    f[0] = a.x; f[1] = a.y; f[2] = b.x; f[3] = b.y;
    f[4] = c.x; f[5] = c.y; f[6] = d.x; f[7] = d.y;
}

__device__ inline void store4h(__half* p, float4 v) {
    __half2 lo = __floats2half2_rn(v.x, v.y);
    __half2 hi = __floats2half2_rn(v.z, v.w);
    uint2 u;
    u.x = *(unsigned int*)&lo;
    u.y = *(unsigned int*)&hi;
    *(uint2*)p = u;
}

// msgX[n,64] f16 = dinv[n] * x[n,:]
__global__ __launch_bounds__(256) void prep_msgx_k(const float* __restrict__ x,
                                                   const float* __restrict__ dinv,
                                                   __half* __restrict__ msg, int n) {
    int t = blockIdx.x * 256 + threadIdx.x;  // one per 4 features
    if (t >= n * 16) return;
    int node = t / 16, q = t % 16;
    float di = dinv[node];
    float4 v = *(const float4*)(x + (long)node * 64 + q * 4);
    v.x *= di; v.y *= di; v.z *= di; v.w *= di;
    store4h(msg + (long)node * 64 + q * 4, v);
}

// out[n,:] = (BIAS? b : 0) + dinv[n] * (msg[n,:] + sum_e msg[col[e],:])
template <int F, bool BIAS>
__global__ __launch_bounds__(256) void agg_f16_k(const __half* __restrict__ msg,
                                                 const int* __restrict__ rowst,
                                                 const int* __restrict__ rowend,
                                                 const int* __restrict__ col,
                                                 const float* __restrict__ dinv,
                                                 const float* __restrict__ b,
                                                 float* __restrict__ out, int n) {
    constexpr int LPN = F / 8;       // lanes per node (8 halves / 16B per lane)
    constexpr int NPB = 256 / LPN;   // nodes per block
    int node = blockIdx.x * NPB + threadIdx.x / LPN;
    int q = threadIdx.x % LPN;
    if (node >= n) return;

    float acc[8];
    load8h(msg + (long)node * F + q * 8, acc);  // self term (dinv folded)

    int beg = rowst[node], end = rowend[node];
    for (int e = beg; e < end; e++) {
        int s = col[e];
        float v[8];
        load8h(msg + (long)s * F + q * 8, v);
#pragma unroll
        for (int j = 0; j < 8; j++) acc[j] += v[j];
    }

    float di = dinv[node];
    float o[8];
#pragma unroll
    for (int j = 0; j < 8; j++) o[j] = di * acc[j];
    if (BIAS) {
#pragma unroll
        for (int j = 0; j < 8; j++) o[j] += b[q * 8 + j];
    }
    float* dst = out + (long)node * F + q * 8;
    *(float4*)dst = make_float4(o[0], o[1], o[2], o[3]);
    *(float4*)(dst + 4) = make_float4(o[4], o[5], o[6], o[7]);
}

// C = epilogue(A[n,K] @ W[K,FOUT]); epilogue: +bias, relu, optional f16 dinv-scale
constexpr int BR = 64;
template <int K, int FOUT, bool BIAS, bool RELU_OUT, bool F16_OUT>
__global__ __launch_bounds__(256) void gemm_k(const float* __restrict__ A,
                                              const float* __restrict__ W,
                                              const float* __restrict__ bias,
                                              const float* __restrict__ dinv,
                                              void* __restrict__ C, int n) {
    constexpr int TPC = FOUT / 4;
    constexpr int RPT = BR * TPC / 256;
    __shared__ float As[BR][K + 4];
    int tid = threadIdx.x;
    int row0 = blockIdx.x * BR;

    for (int i = tid * 4; i < BR * K; i += 1024) {
        int r = i / K, k = i % K;
        int row = row0 + r;
        float4 v = make_float4(0.f, 0.f, 0.f, 0.f);
        if (row < n) v = *(const float4*)(A + (long)row * K + k);
        *(float4*)&As[r][k] = v;
    }
    __syncthreads();

    int tx = tid % TPC, ty = tid / TPC;
    float4 acc[RPT];
#pragma unroll
    for (int i = 0; i < RPT; i++) acc[i] = make_float4(0.f, 0.f, 0.f, 0.f);

    for (int k = 0; k < K; k += 4) {
        float4 w0 = *(const float4*)(W + (k + 0) * FOUT + tx * 4);
        float4 w1 = *(const float4*)(W + (k + 1) * FOUT + tx * 4);
        float4 w2 = *(const float4*)(W + (k + 2) * FOUT + tx * 4);
        float4 w3 = *(const float4*)(W + (k + 3) * FOUT + tx * 4);
#pragma unroll
        for (int i = 0; i < RPT; i++) {
            int r = ty * RPT + i;
            float4 a = *(float4*)&As[r][k];
            acc[i].x += a.x * w0.x + a.y * w1.x + a.z * w2.x + a.w * w3.x;
            acc[i].y += a.x * w0.y + a.y * w1.y + a.z * w2.y + a.w * w3.y;
            acc[i].z += a.x * w0.z + a.y * w1.z + a.z * w2.z + a.w * w3.z;
            acc[i].w += a.x * w0.w + a.y * w1.w + a.z * w2.w + a.w * w3.w;
        }
    }

    float4 bb = make_float4(0.f, 0.f, 0.f, 0.f);
    if (BIAS) bb = *(const float4*)(bias + tx * 4);
#pragma unroll
    for (int i = 0; i < RPT; i++) {
        int row = row0 + ty * RPT + i;
        if (row >= n) continue;
        float4 v = acc[i];
        if (BIAS) { v.x += bb.x; v.y += bb.y; v.z += bb.z; v.w += bb.w; }
        if (RELU_OUT) {
            v.x = fmaxf(v.x, 0.f); v.y = fmaxf(v.y, 0.f);
            v.z = fmaxf(v.z, 0.f); v.w = fmaxf(v.w, 0.f);
        }
        if (F16_OUT) {
            float di = dinv[row];
            v.x *= di; v.y *= di; v.z *= di; v.w *= di;
            store4h((__half*)C + (long)row * FOUT + tx * 4, v);
        } else {
            *(float4*)((float*)C + (long)row * FOUT + tx * 4) = v;
        }
    }
}

extern "C" void kernel_launch(void* const* d_in, const int* in_sizes, int n_in,
                              void* d_out, int out_size, void* d_ws, size_t ws_size,
                              hipStream_t stream) {
    const float* x  = (const float*)d_in[0];
    const int*   ei = (const int*)d_in[1];
    const float* W1 = (const float*)d_in[2];
    const float* b1 = (const float*)d_in[3];
    const float* W2 = (const float*)d_in[4];
    const float* b2 = (const float*)d_in[5];
    const float* W3 = (const float*)d_in[6];
    const float* b3 = (const float*)d_in[7];
    float* out = (float*)d_out;

    const int N = in_sizes[0] / 64;
    const int E = in_sizes[1] / 2;
    const int* src = ei;
    const int* dst = ei + E;

    // workspace carve-up
    int*   cnt    = (int*)d_ws;              // N
    int*   rowst  = cnt + N;                 // N (excl scan in place)
    int*   cursor = rowst + N;               // N (becomes row end after fill)
    int*   bsums  = cursor + N;              // 1024
    float* dinv   = (float*)(bsums + 1024);  // N
    int*   col    = (int*)(dinv + N);        // E
    float* P      = (float*)(col + E);       // N*128 f32 worth (ping)
    float* Q      = P + (long)N * 128;       // N*128 f32 worth (pong)

    const int nb = (N + 255) / 256;
    const int eb = (E + 255) / 256;
    const int gb = (N + BR - 1) / BR;

    // ---- CSR build + norms ----
    zero_int_k<<<nb, 256, 0, stream>>>(cnt, N);
    count_k<<<eb, 256, 0, stream>>>(dst, cnt, E);
    scan_blocks_k<<<nb, 256, 0, stream>>>(cnt, rowst, bsums, N);
    scan_sums_k<<<1, 512, 0, stream>>>(bsums, nb);
    finish_scan_k<<<nb, 256, 0, stream>>>(rowst, cursor, bsums, cnt, dinv, N);
    fill_k<<<eb, 256, 0, stream>>>(src, dst, cursor, col, E);

    __half* msgX  = (__half*)P;   // N x 64 f16
    float*  aggX  = Q;            // N x 64 f32
    __half* msg1  = (__half*)P;   // N x 128 f16
    float*  aggH1 = Q;            // N x 128 f32
    float*  h2    = P;            // N x 128 f32
    __half* msg3  = (__half*)Q;   // N x 64 f16

    // ---- layer 1: aggregate x at 64, then GEMM 64->128 ----
    prep_msgx_k<<<(N * 16 + 255) / 256, 256, 0, stream>>>(x, dinv, msgX, N);
    agg_f16_k<64, false><<<(N + 31) / 32, 256, 0, stream>>>(msgX, rowst, cursor, col,
                                                            dinv, nullptr, aggX, N);
    gemm_k<64, 128, true, true, true><<<gb, 256, 0, stream>>>(aggX, W1, b1, dinv,
                                                              (void*)msg1, N);

    // ---- layer 2: aggregate msg1 at 128, then GEMM 128->128 ----
    agg_f16_k<128, false><<<(N + 15) / 16, 256, 0, stream>>>(msg1, rowst, cursor, col,
                                                             dinv, nullptr, aggH1, N);
    gemm_k<128, 128, true, true, false><<<gb, 256, 0, stream>>>(aggH1, W2, b2, nullptr,
                                                                (void*)h2, N);

    // ---- layer 3: GEMM 128->64 (emit f16 msg), aggregate at 64 -> out ----
    gemm_k<128, 64, false, false, true><<<gb, 256, 0, stream>>>(h2, W3, nullptr, dinv,
                                                                (void*)msg3, N);
    agg_f16_k<64, true><<<(N + 31) / 32, 256, 0, stream>>>(msg3, rowst, cursor, col,
                                                           dinv, b3, out, N);
}

// Round 4
// 556.929 us; speedup vs baseline: 12.4675x; 1.0095x over previous
//
#include <hip/hip_runtime.h>
#include <hip/hip_bf16.h>
#include <hip/hip_fp16.h>

// ---------------------------------------------------------------------------
// GCN 3-layer forward. N=100000, E=1600000, F: 64 -> 128 -> 128 -> 64.
// R4: bucketed CSR build (kills fill_k's 16x write amplification).
//   bhist (LDS-priv, padded cursors) -> bucket scan (1 block)
//   part: (src,dst) 8B append into bucket regions (L2 write-combined)
//   finalize: block-per-bucket LDS count/scan/place + dinv + fused msgX prep
//   then: aggX -> gemm1(f16 msg out) -> agg128 -> gemm2 -> gemm3(f16) -> agg64
// ---------------------------------------------------------------------------

constexpr int BSHIFT = 7;                 // 128 nodes per bucket
constexpr int BNODES = 1 << BSHIFT;
constexpr int CAP = 3072;                 // LDS stage capacity (mean 2048, sd ~45)
constexpr int PAD = 16;                   // cursor padding: one per 64B line

// ---- f16 helpers ----------------------------------------------------------
__device__ inline void load8h(const __half* p, float* f) {
    uint4 raw = *(const uint4*)p;  // 16B = 8 halves
    const __half2* h = (const __half2*)&raw;
    float2 a = __half22float2(h[0]);
    float2 b = __half22float2(h[1]);
    float2 c = __half22float2(h[2]);
    float2 d = __half22float2(h[3]);
    f[0] = a.x; f[1] = a.y; f[2] = b.x; f[3] = b.y;
    f[4] = c.x; f[5] = c.y; f[6] = d.x; f[7] = d.y;
}

__device__ inline void store4h(__half* p, float4 v) {
    __half2 lo = __floats2half2_rn(v.x, v.y);
    __half2 hi = __floats2half2_rn(v.z, v.w);
    uint2 u;
    u.x = *(unsigned int*)&lo;
    u.y = *(unsigned int*)&hi;
    *(uint2*)p = u;
}

// ---- CSR build ------------------------------------------------------------
__global__ __launch_bounds__(256) void bhist_k(const int* __restrict__ dst,
                                               int* __restrict__ bhist,
                                               int E, int nbuck) {
    __shared__ int h[1024];
    for (int i = threadIdx.x; i < nbuck; i += 256) h[i] = 0;
    __syncthreads();
    int stride = gridDim.x * 256;
    for (int e = blockIdx.x * 256 + threadIdx.x; e < E; e += stride)
        atomicAdd(&h[dst[e] >> BSHIFT], 1);
    __syncthreads();
    for (int i = threadIdx.x; i < nbuck; i += 256)
        if (h[i]) atomicAdd(&bhist[i * PAD], h[i]);
}

// 1 block: exclusive scan of nbuck (<=1024) bucket counts -> bbase + cursors
__global__ __launch_bounds__(1024) void bscan_k(const int* __restrict__ bhist,
                                                int* __restrict__ bbase,
                                                int* __restrict__ bcursor,
                                                int nbuck, int E) {
    __shared__ int s[1024];
    int tid = threadIdx.x;
    int v = (tid < nbuck) ? bhist[tid * PAD] : 0;
    s[tid] = v;
    __syncthreads();
    for (int off = 1; off < 1024; off <<= 1) {
        int t = (tid >= off) ? s[tid - off] : 0;
        __syncthreads();
        s[tid] += t;
        __syncthreads();
    }
    if (tid < nbuck) {
        int ex = s[tid] - v;
        bbase[tid] = ex;
        bcursor[tid * PAD] = ex;
    }
    if (tid == 0) bbase[nbuck] = E;
}

// partition edges into bucket-contiguous regions (8B packed entries)
__global__ __launch_bounds__(256) void part_k(const int* __restrict__ src,
                                              const int* __restrict__ dst,
                                              int* __restrict__ bcursor,
                                              uint2* __restrict__ ebuf, int E) {
    int e = blockIdx.x * 256 + threadIdx.x;
    if (e >= E) return;
    int d = dst[e];
    int b = d >> BSHIFT;
    int pos = atomicAdd(&bcursor[b * PAD], 1);
    ebuf[pos] = make_uint2((unsigned)src[e], (unsigned)d);
}

// block-per-bucket: count+scan+place in LDS; emit rowst/rowend/dinv/col;
// fused msgX prep: msgX[n,64] f16 = dinv[n]*x[n,:]
__global__ __launch_bounds__(256) void finalize_k(const uint2* __restrict__ ebuf,
                                                  const int* __restrict__ bbase,
                                                  int* __restrict__ rowst,
                                                  int* __restrict__ rowend,
                                                  float* __restrict__ dinv,
                                                  int* __restrict__ col,
                                                  const float* __restrict__ x,
                                                  __half* __restrict__ msgX, int N) {
    __shared__ uint2 se[CAP];
    __shared__ int cnt_s[BNODES];
    __shared__ int scan_s[BNODES];
    __shared__ int cur_s[BNODES];
    __shared__ float di_s[BNODES];

    int b = blockIdx.x, tid = threadIdx.x;
    int node0 = b << BSHIFT;
    int nn = min(BNODES, N - node0);
    int beg = bbase[b], end = bbase[b + 1];
    int m = end - beg;

    if (tid < BNODES) cnt_s[tid] = 0;
    __syncthreads();

    int cap = m < CAP ? m : CAP;
    for (int i = tid; i < cap; i += 256) {
        uint2 e = ebuf[beg + i];
        se[i] = e;
        atomicAdd(&cnt_s[e.y - node0], 1);
    }
    for (int i = CAP + tid; i < m; i += 256) {  // spill (statistically never)
        uint2 e = ebuf[beg + i];
        atomicAdd(&cnt_s[e.y - node0], 1);
    }
    __syncthreads();

    // inclusive scan of cnt_s into scan_s
    int v = (tid < BNODES) ? cnt_s[tid] : 0;
    if (tid < BNODES) scan_s[tid] = v;
    __syncthreads();
    for (int off = 1; off < BNODES; off <<= 1) {
        int t = 0;
        if (tid < BNODES && tid >= off) t = scan_s[tid - off];
        __syncthreads();
        if (tid < BNODES) scan_s[tid] += t;
        __syncthreads();
    }
    if (tid < nn) {
        int ex = scan_s[tid] - v;  // exclusive
        int st = beg + ex;
        rowst[node0 + tid] = st;
        rowend[node0 + tid] = st + v;
        float di = rsqrtf((float)v + 1.0f);
        dinv[node0 + tid] = di;
        di_s[tid] = di;
        cur_s[tid] = ex;
    }
    __syncthreads();

    // place col (dense 8KB window per block -> full-line writes)
    for (int i = tid; i < cap; i += 256) {
        uint2 e = se[i];
        int l = e.y - node0;
        int p = atomicAdd(&cur_s[l], 1);
        col[beg + p] = (int)e.x;
    }
    for (int i = CAP + tid; i < m; i += 256) {
        uint2 e = ebuf[beg + i];
        int l = e.y - node0;
        int p = atomicAdd(&cur_s[l], 1);
        col[beg + p] = (int)e.x;
    }

    // fused msgX prep: nn nodes x 16 float4 chunks
    for (int t = tid; t < nn * 16; t += 256) {
        int nl = t >> 4, q = t & 15;
        int node = node0 + nl;
        float4 vx = *(const float4*)(x + (long)node * 64 + q * 4);
        float di = di_s[nl];
        vx.x *= di; vx.y *= di; vx.z *= di; vx.w *= di;
        store4h(msgX + (long)node * 64 + q * 4, vx);
    }
}

// ---- aggregation ----------------------------------------------------------
// out[n,:] = (BIAS? b : 0) + dinv[n] * (msg[n,:] + sum_e msg[col[e],:])
template <int F, bool BIAS>
__global__ __launch_bounds__(256) void agg_f16_k(const __half* __restrict__ msg,
                                                 const int* __restrict__ rowst,
                                                 const int* __restrict__ rowend,
                                                 const int* __restrict__ col,
                                                 const float* __restrict__ dinv,
                                                 const float* __restrict__ b,
                                                 float* __restrict__ out, int n) {
    constexpr int LPN = F / 8;       // lanes per node (16B per lane)
    constexpr int NPB = 256 / LPN;   // nodes per block
    int node = blockIdx.x * NPB + threadIdx.x / LPN;
    int q = threadIdx.x % LPN;
    if (node >= n) return;

    float acc[8];
    load8h(msg + (long)node * F + q * 8, acc);  // self term (dinv folded)

    int beg = rowst[node], end = rowend[node];
    for (int e = beg; e < end; e++) {
        int s = col[e];
        float v[8];
        load8h(msg + (long)s * F + q * 8, v);
#pragma unroll
        for (int j = 0; j < 8; j++) acc[j] += v[j];
    }

    float di = dinv[node];
    float o[8];
#pragma unroll
    for (int j = 0; j < 8; j++) o[j] = di * acc[j];
    if (BIAS) {
#pragma unroll
        for (int j = 0; j < 8; j++) o[j] += b[q * 8 + j];
    }
    float* dst = out + (long)node * F + q * 8;
    *(float4*)dst = make_float4(o[0], o[1], o[2], o[3]);
    *(float4*)(dst + 4) = make_float4(o[4], o[5], o[6], o[7]);
}

// ---- dense transform ------------------------------------------------------
// C = epilogue(A[n,K] @ W[K,FOUT]); epilogue: +bias, relu, optional f16 dinv-scale
constexpr int BR = 64;
template <int K, int FOUT, bool BIAS, bool RELU_OUT, bool F16_OUT>
__global__ __launch_bounds__(256) void gemm_k(const float* __restrict__ A,
                                              const float* __restrict__ W,
                                              const float* __restrict__ bias,
                                              const float* __restrict__ dinv,
                                              void* __restrict__ C, int n) {
    constexpr int TPC = FOUT / 4;
    constexpr int RPT = BR * TPC / 256;
    __shared__ float As[BR][K + 4];
    int tid = threadIdx.x;
    int row0 = blockIdx.x * BR;

    for (int i = tid * 4; i < BR * K; i += 1024) {
        int r = i / K, k = i % K;
        int row = row0 + r;
        float4 v = make_float4(0.f, 0.f, 0.f, 0.f);
        if (row < n) v = *(const float4*)(A + (long)row * K + k);
        *(float4*)&As[r][k] = v;
    }
    __syncthreads();

    int tx = tid % TPC, ty = tid / TPC;
    float4 acc[RPT];
#pragma unroll
    for (int i = 0; i < RPT; i++) acc[i] = make_float4(0.f, 0.f, 0.f, 0.f);

    for (int k = 0; k < K; k += 4) {
        float4 w0 = *(const float4*)(W + (k + 0) * FOUT + tx * 4);
        float4 w1 = *(const float4*)(W + (k + 1) * FOUT + tx * 4);
        float4 w2 = *(const float4*)(W + (k + 2) * FOUT + tx * 4);
        float4 w3 = *(const float4*)(W + (k + 3) * FOUT + tx * 4);
#pragma unroll
        for (int i = 0; i < RPT; i++) {
            int r = ty * RPT + i;
            float4 a = *(float4*)&As[r][k];
            acc[i].x += a.x * w0.x + a.y * w1.x + a.z * w2.x + a.w * w3.x;
            acc[i].y += a.x * w0.y + a.y * w1.y + a.z * w2.y + a.w * w3.y;
            acc[i].z += a.x * w0.z + a.y * w1.z + a.z * w2.z + a.w * w3.z;
            acc[i].w += a.x * w0.w + a.y * w1.w + a.z * w2.w + a.w * w3.w;
        }
    }

    float4 bb = make_float4(0.f, 0.f, 0.f, 0.f);
    if (BIAS) bb = *(const float4*)(bias + tx * 4);
#pragma unroll
    for (int i = 0; i < RPT; i++) {
        int row = row0 + ty * RPT + i;
        if (row >= n) continue;
        float4 v = acc[i];
        if (BIAS) { v.x += bb.x; v.y += bb.y; v.z += bb.z; v.w += bb.w; }
        if (RELU_OUT) {
            v.x = fmaxf(v.x, 0.f); v.y = fmaxf(v.y, 0.f);
            v.z = fmaxf(v.z, 0.f); v.w = fmaxf(v.w, 0.f);
        }
        if (F16_OUT) {
            float di = dinv[row];
            v.x *= di; v.y *= di; v.z *= di; v.w *= di;
            store4h((__half*)C + (long)row * FOUT + tx * 4, v);
        } else {
            *(float4*)((float*)C + (long)row * FOUT + tx * 4) = v;
        }
    }
}

extern "C" void kernel_launch(void* const* d_in, const int* in_sizes, int n_in,
                              void* d_out, int out_size, void* d_ws, size_t ws_size,
                              hipStream_t stream) {
    const float* x  = (const float*)d_in[0];
    const int*   ei = (const int*)d_in[1];
    const float* W1 = (const float*)d_in[2];
    const float* b1 = (const float*)d_in[3];
    const float* W2 = (const float*)d_in[4];
    const float* b2 = (const float*)d_in[5];
    const float* W3 = (const float*)d_in[6];
    const float* b3 = (const float*)d_in[7];
    float* out = (float*)d_out;

    const int N = in_sizes[0] / 64;
    const int E = in_sizes[1] / 2;
    const int* src = ei;
    const int* dst = ei + E;
    const int nbuck = (N + BNODES - 1) >> BSHIFT;  // 782 for N=100000

    // workspace carve-up
    int*   bhist   = (int*)d_ws;                  // nbuck*PAD
    int*   bcursor = bhist + nbuck * PAD;         // nbuck*PAD
    int*   bbase   = bcursor + nbuck * PAD;       // nbuck+1
    int*   rowst   = bbase + nbuck + 1;           // N
    int*   rowend  = rowst + N;                   // N
    float* dinv    = (float*)(rowend + N);        // N
    int*   col     = (int*)(dinv + N);            // E
    float* P       = (float*)(col + E);           // N*128 f32 worth
    float* Q       = P + (long)N * 128;           // N*128 f32 worth

    __half* msgX  = (__half*)P;       // N x 64 f16
    uint2*  ebuf  = (uint2*)Q;        // E x 8B (dead before aggX written)
    float*  aggX  = Q;                // N x 64 f32
    __half* msg1  = (__half*)P;       // N x 128 f16
    float*  aggH1 = Q;                // N x 128 f32
    float*  h2    = P;                // N x 128 f32
    __half* msg3  = (__half*)Q;       // N x 64 f16

    const int eb = (E + 255) / 256;
    const int gb = (N + BR - 1) / BR;

    // ---- CSR build (bucketed) ----
    hipMemsetAsync(bhist, 0, (size_t)nbuck * PAD * sizeof(int), stream);
    bhist_k<<<256, 256, 0, stream>>>(dst, bhist, E, nbuck);
    bscan_k<<<1, 1024, 0, stream>>>(bhist, bbase, bcursor, nbuck, E);
    part_k<<<eb, 256, 0, stream>>>(src, dst, bcursor, ebuf, E);
    finalize_k<<<nbuck, 256, 0, stream>>>(ebuf, bbase, rowst, rowend, dinv, col,
                                          x, msgX, N);

    // ---- layer 1: aggregate x at 64, then GEMM 64->128 ----
    agg_f16_k<64, false><<<(N + 31) / 32, 256, 0, stream>>>(msgX, rowst, rowend, col,
                                                            dinv, nullptr, aggX, N);
    gemm_k<64, 128, true, true, true><<<gb, 256, 0, stream>>>(aggX, W1, b1, dinv,
                                                              (void*)msg1, N);

    // ---- layer 2: aggregate msg1 at 128, then GEMM 128->128 ----
    agg_f16_k<128, false><<<(N + 15) / 16, 256, 0, stream>>>(msg1, rowst, rowend, col,
                                                             dinv, nullptr, aggH1, N);
    gemm_k<128, 128, true, true, false><<<gb, 256, 0, stream>>>(aggH1, W2, b2, nullptr,
                                                                (void*)h2, N);

    // ---- layer 3: GEMM 128->64 (emit f16 msg), aggregate at 64 -> out ----
    gemm_k<128, 64, false, false, true><<<gb, 256, 0, stream>>>(h2, W3, nullptr, dinv,
                                                                (void*)msg3, N);
    agg_f16_k<64, true><<<(N + 31) / 32, 256, 0, stream>>>(msg3, rowst, rowend, col,
                                                           dinv, b3, out, N);
}

// Round 5
// 537.034 us; speedup vs baseline: 12.9294x; 1.0370x over previous
//
#include <hip/hip_runtime.h>
#include <hip/hip_bf16.h>
#include <hip/hip_fp16.h>

// ---------------------------------------------------------------------------
// GCN 3-layer forward. N=100000, E=1600000, F: 64 -> 128 -> 128 -> 64.
// R5: block-private counting-sort CSR build (single-writer cache lines).
//   phist: B=64 blocks, LDS hist per chunk -> hist[block][bucket] (contiguous)
//   scan(hist flat) -> offs ; scan(btot) -> bbase
//   part2: block-private cursors, 4B packed entries, contiguous block region
//   finalize: block-per-bucket gather 64 segments -> LDS count/scan/place
//             + dinv + fused f16 msgX prep
//   then: aggX -> gemm1(f16 out) -> agg128 -> gemm2 -> gemm3(f16) -> agg64
// ---------------------------------------------------------------------------

constexpr int BSHIFT = 7;                 // 128 nodes per bucket
constexpr int BNODES = 1 << BSHIFT;
constexpr int PB     = 64;                // partition blocks (block-private chunks)
constexpr int CAP    = 4096;              // LDS stage capacity (mean 2048, sd ~45)

// ---- f16 helpers ----------------------------------------------------------
__device__ inline void load8h(const __half* p, float* f) {
    uint4 raw = *(const uint4*)p;  // 16B = 8 halves
    const __half2* h = (const __half2*)&raw;
    float2 a = __half22float2(h[0]);
    float2 b = __half22float2(h[1]);
    float2 c = __half22float2(h[2]);
    float2 d = __half22float2(h[3]);
    f[0] = a.x; f[1] = a.y; f[2] = b.x; f[3] = b.y;
    f[4] = c.x; f[5] = c.y; f[6] = d.x; f[7] = d.y;
}

__device__ inline void store4h(__half* p, float4 v) {
    __half2 lo = __floats2half2_rn(v.x, v.y);
    __half2 hi = __floats2half2_rn(v.z, v.w);
    uint2 u;
    u.x = *(unsigned int*)&lo;
    u.y = *(unsigned int*)&hi;
    *(uint2*)p = u;
}

// ---- CSR build ------------------------------------------------------------
// block j histograms its chunk; writes hist[j*nbuck..] contiguously; btot +=
__global__ __launch_bounds__(256) void phist_k(const int* __restrict__ dst,
                                               int* __restrict__ hist,
                                               int* __restrict__ btot,
                                               int E, int nbuck, int chunk) {
    __shared__ int h[1024];
    for (int i = threadIdx.x; i < nbuck; i += 256) h[i] = 0;
    __syncthreads();
    int beg = blockIdx.x * chunk;
    int end = min(E, beg + chunk);
    for (int e = beg + threadIdx.x; e < end; e += 256)
        atomicAdd(&h[dst[e] >> BSHIFT], 1);
    __syncthreads();
    for (int i = threadIdx.x; i < nbuck; i += 256) {
        int v = h[i];
        hist[(long)blockIdx.x * nbuck + i] = v;   // contiguous full-line writes
        if (v) atomicAdd(&btot[i], v);
    }
}

// generic 2-level exclusive scan over n ints (n <= 512*256)
__global__ __launch_bounds__(256) void scan_blocks_k(const int* __restrict__ in,
                                                     int* __restrict__ excl,
                                                     int* __restrict__ bsums, int n) {
    __shared__ int s[256];
    int tid = threadIdx.x;
    int i = blockIdx.x * 256 + tid;
    int v = (i < n) ? in[i] : 0;
    s[tid] = v;
    __syncthreads();
    for (int off = 1; off < 256; off <<= 1) {
        int t = (tid >= off) ? s[tid - off] : 0;
        __syncthreads();
        s[tid] += t;
        __syncthreads();
    }
    if (i < n) excl[i] = s[tid] - v;
    if (tid == 255) bsums[blockIdx.x] = s[255];
}

__global__ __launch_bounds__(512) void scan_sums_k(int* bsums, int nb) {
    __shared__ int s[512];
    int tid = threadIdx.x;
    int v = (tid < nb) ? bsums[tid] : 0;
    s[tid] = v;
    __syncthreads();
    for (int off = 1; off < 512; off <<= 1) {
        int t = (tid >= off) ? s[tid - off] : 0;
        __syncthreads();
        s[tid] += t;
        __syncthreads();
    }
    if (tid < nb) bsums[tid] = s[tid] - v;  // exclusive
}

__global__ __launch_bounds__(256) void finish_offs_k(int* __restrict__ offs,
                                                     const int* __restrict__ bsums,
                                                     int n) {
    int i = blockIdx.x * 256 + threadIdx.x;
    if (i < n) offs[i] += bsums[blockIdx.x];
}

// 1 block: exclusive scan of btot (nbuck <= 1024) -> bbase
__global__ __launch_bounds__(1024) void bbase_scan_k(const int* __restrict__ btot,
                                                     int* __restrict__ bbase,
                                                     int nbuck, int E) {
    __shared__ int s[1024];
    int tid = threadIdx.x;
    int v = (tid < nbuck) ? btot[tid] : 0;
    s[tid] = v;
    __syncthreads();
    for (int off = 1; off < 1024; off <<= 1) {
        int t = (tid >= off) ? s[tid - off] : 0;
        __syncthreads();
        s[tid] += t;
        __syncthreads();
    }
    if (tid < nbuck) bbase[tid] = s[tid] - v;
    if (tid == 0) bbase[nbuck] = E;
}

// block-private partition: each block writes only its own contiguous region
__global__ __launch_bounds__(256) void part2_k(const int* __restrict__ src,
                                               const int* __restrict__ dst,
                                               const int* __restrict__ offs,
                                               unsigned* __restrict__ ebuf,
                                               int E, int nbuck, int chunk) {
    __shared__ int cur[1024];
    for (int i = threadIdx.x; i < nbuck; i += 256)
        cur[i] = offs[(long)blockIdx.x * nbuck + i];
    __syncthreads();
    int beg = blockIdx.x * chunk;
    int end = min(E, beg + chunk);
    for (int e = beg + threadIdx.x; e < end; e += 256) {
        int d = dst[e];
        int b = d >> BSHIFT;
        int pos = atomicAdd(&cur[b], 1);                  // LDS atomic
        ebuf[pos] = ((unsigned)(d & (BNODES - 1)) << 25) | (unsigned)src[e];
    }
}

// block-per-bucket: gather PB segments -> LDS; count/scan/place; dinv; msgX
__global__ __launch_bounds__(256) void finalize_k(const unsigned* __restrict__ ebuf,
                                                  const int* __restrict__ hist,
                                                  const int* __restrict__ offs,
                                                  const int* __restrict__ bbase,
                                                  int nbuck,
                                                  int* __restrict__ rowst,
                                                  int* __restrict__ rowend,
                                                  float* __restrict__ dinv,
                                                  int* __restrict__ col,
                                                  const float* __restrict__ x,
                                                  __half* __restrict__ msgX, int N) {
    __shared__ unsigned se[CAP];
    __shared__ int cj[PB], sj[PB], sb[PB];
    __shared__ int cnt_s[BNODES], scan_s[BNODES], cur_s[BNODES];
    __shared__ float di_s[BNODES];
    __shared__ int m_s;

    int b = blockIdx.x, tid = threadIdx.x;
    int node0 = b << BSHIFT;
    int nn = min(BNODES, N - node0);
    int beg = bbase[b];

    if (tid < PB) {
        cj[tid] = hist[(long)tid * nbuck + b];
        sj[tid] = offs[(long)tid * nbuck + b];
    }
    if (tid < BNODES) cnt_s[tid] = 0;
    __syncthreads();

    // exclusive bases of the PB segments within this bucket (scan cj)
    if (tid < PB) sb[tid] = cj[tid];
    __syncthreads();
    for (int off = 1; off < PB; off <<= 1) {
        int t = 0;
        if (tid < PB && tid >= off) t = sb[tid - off];
        __syncthreads();
        if (tid < PB) sb[tid] += t;
        __syncthreads();
    }
    if (tid == PB - 1) m_s = sb[PB - 1];
    __syncthreads();
    int m = m_s;

    // gather segments into LDS: 4 threads per segment
    {
        int j = tid >> 2, lane = tid & 3;
        int base = sb[j] - cj[j], c = cj[j], s0 = sj[j];
        for (int k = lane; k < c; k += 4) {
            unsigned e = ebuf[s0 + k];
            int idx = base + k;
            if (idx < CAP) se[idx] = e;
            else atomicAdd(&cnt_s[e >> 25], 1);  // overflow: count directly
        }
    }
    __syncthreads();

    int mcap = m < CAP ? m : CAP;
    for (int i = tid; i < mcap; i += 256) atomicAdd(&cnt_s[se[i] >> 25], 1);
    __syncthreads();

    // inclusive scan of cnt_s
    int v = (tid < BNODES) ? cnt_s[tid] : 0;
    if (tid < BNODES) scan_s[tid] = v;
    __syncthreads();
    for (int off = 1; off < BNODES; off <<= 1) {
        int t = 0;
        if (tid < BNODES && tid >= off) t = scan_s[tid - off];
        __syncthreads();
        if (tid < BNODES) scan_s[tid] += t;
        __syncthreads();
    }
    if (tid < nn) {
        int ex = scan_s[tid] - v;  // exclusive
        int st = beg + ex;
        rowst[node0 + tid] = st;
        rowend[node0 + tid] = st + v;
        float di = rsqrtf((float)v + 1.0f);
        dinv[node0 + tid] = di;
        di_s[tid] = di;
        cur_s[tid] = ex;
    }
    __syncthreads();

    // place col (dense contiguous bucket window -> full-line writes)
    for (int i = tid; i < mcap; i += 256) {
        unsigned e = se[i];
        int p = atomicAdd(&cur_s[e >> 25], 1);
        col[beg + p] = (int)(e & 0x1FFFFFFu);
    }
    if (m > CAP) {  // overflow spill (statistically never)
        int j = tid >> 2, lane = tid & 3;
        int base = sb[j] - cj[j], c = cj[j], s0 = sj[j];
        for (int k = lane; k < c; k += 4) {
            int idx = base + k;
            if (idx >= CAP) {
                unsigned e = ebuf[s0 + k];
                int p = atomicAdd(&cur_s[e >> 25], 1);
                col[beg + p] = (int)(e & 0x1FFFFFFu);
            }
        }
    }

    // fused msgX prep: msgX[n,64] f16 = dinv[n] * x[n,:]
    for (int t = tid; t < nn * 16; t += 256) {
        int nl = t >> 4, q = t & 15;
        int node = node0 + nl;
        float4 vx = *(const float4*)(x + (long)node * 64 + q * 4);
        float di = di_s[nl];
        vx.x *= di; vx.y *= di; vx.z *= di; vx.w *= di;
        store4h(msgX + (long)node * 64 + q * 4, vx);
    }
}

// ---- aggregation ----------------------------------------------------------
// out[n,:] = (BIAS? b : 0) + dinv[n] * (msg[n,:] + sum_e msg[col[e],:])
template <int F, bool BIAS>
__global__ __launch_bounds__(256) void agg_f16_k(const __half* __restrict__ msg,
                                                 const int* __restrict__ rowst,
                                                 const int* __restrict__ rowend,
                                                 const int* __restrict__ col,
                                                 const float* __restrict__ dinv,
                                                 const float* __restrict__ b,
                                                 float* __restrict__ out, int n) {
    constexpr int LPN = F / 8;       // lanes per node (16B per lane)
    constexpr int NPB = 256 / LPN;   // nodes per block
    int node = blockIdx.x * NPB + threadIdx.x / LPN;
    int q = threadIdx.x % LPN;
    if (node >= n) return;

    float acc[8];
    load8h(msg + (long)node * F + q * 8, acc);  // self term (dinv folded)

    int beg = rowst[node], end = rowend[node];
    for (int e = beg; e < end; e++) {
        int s = col[e];
        float v[8];
        load8h(msg + (long)s * F + q * 8, v);
#pragma unroll
        for (int j = 0; j < 8; j++) acc[j] += v[j];
    }

    float di = dinv[node];
    float o[8];
#pragma unroll
    for (int j = 0; j < 8; j++) o[j] = di * acc[j];
    if (BIAS) {
#pragma unroll
        for (int j = 0; j < 8; j++) o[j] += b[q * 8 + j];
    }
    float* dst = out + (long)node * F + q * 8;
    *(float4*)dst = make_float4(o[0], o[1], o[2], o[3]);
    *(float4*)(dst + 4) = make_float4(o[4], o[5], o[6], o[7]);
}

// ---- dense transform ------------------------------------------------------
constexpr int BR = 64;
template <int K, int FOUT, bool BIAS, bool RELU_OUT, bool F16_OUT>
__global__ __launch_bounds__(256) void gemm_k(const float* __restrict__ A,
                                              const float* __restrict__ W,
                                              const float* __restrict__ bias,
                                              const float* __restrict__ dinv,
                                              void* __restrict__ C, int n) {
    constexpr int TPC = FOUT / 4;
    constexpr int RPT = BR * TPC / 256;
    __shared__ float As[BR][K + 4];
    int tid = threadIdx.x;
    int row0 = blockIdx.x * BR;

    for (int i = tid * 4; i < BR * K; i += 1024) {
        int r = i / K, k = i % K;
        int row = row0 + r;
        float4 v = make_float4(0.f, 0.f, 0.f, 0.f);
        if (row < n) v = *(const float4*)(A + (long)row * K + k);
        *(float4*)&As[r][k] = v;
    }
    __syncthreads();

    int tx = tid % TPC, ty = tid / TPC;
    float4 acc[RPT];
#pragma unroll
    for (int i = 0; i < RPT; i++) acc[i] = make_float4(0.f, 0.f, 0.f, 0.f);

    for (int k = 0; k < K; k += 4) {
        float4 w0 = *(const float4*)(W + (k + 0) * FOUT + tx * 4);
        float4 w1 = *(const float4*)(W + (k + 1) * FOUT + tx * 4);
        float4 w2 = *(const float4*)(W + (k + 2) * FOUT + tx * 4);
        float4 w3 = *(const float4*)(W + (k + 3) * FOUT + tx * 4);
#pragma unroll
        for (int i = 0; i < RPT; i++) {
            int r = ty * RPT + i;
            float4 a = *(float4*)&As[r][k];
            acc[i].x += a.x * w0.x + a.y * w1.x + a.z * w2.x + a.w * w3.x;
            acc[i].y += a.x * w0.y + a.y * w1.y + a.z * w2.y + a.w * w3.y;
            acc[i].z += a.x * w0.z + a.y * w1.z + a.z * w2.z + a.w * w3.z;
            acc[i].w += a.x * w0.w + a.y * w1.w + a.z * w2.w + a.w * w3.w;
        }
    }

    float4 bb = make_float4(0.f, 0.f, 0.f, 0.f);
    if (BIAS) bb = *(const float4*)(bias + tx * 4);
#pragma unroll
    for (int i = 0; i < RPT; i++) {
        int row = row0 + ty * RPT + i;
        if (row >= n) continue;
        float4 v = acc[i];
        if (BIAS) { v.x += bb.x; v.y += bb.y; v.z += bb.z; v.w += bb.w; }
        if (RELU_OUT) {
            v.x = fmaxf(v.x, 0.f); v.y = fmaxf(v.y, 0.f);
            v.z = fmaxf(v.z, 0.f); v.w = fmaxf(v.w, 0.f);
        }
        if (F16_OUT) {
            float di = dinv[row];
            v.x *= di; v.y *= di; v.z *= di; v.w *= di;
            store4h((__half*)C + (long)row * FOUT + tx * 4, v);
        } else {
            *(float4*)((float*)C + (long)row * FOUT + tx * 4) = v;
        }
    }
}

extern "C" void kernel_launch(void* const* d_in, const int* in_sizes, int n_in,
                              void* d_out, int out_size, void* d_ws, size_t ws_size,
                              hipStream_t stream) {
    const float* x  = (const float*)d_in[0];
    const int*   ei = (const int*)d_in[1];
    const float* W1 = (const float*)d_in[2];
    const float* b1 = (const float*)d_in[3];
    const float* W2 = (const float*)d_in[4];
    const float* b2 = (const float*)d_in[5];
    const float* W3 = (const float*)d_in[6];
    const float* b3 = (const float*)d_in[7];
    float* out = (float*)d_out;

    const int N = in_sizes[0] / 64;
    const int E = in_sizes[1] / 2;
    const int* src = ei;
    const int* dst = ei + E;
    const int nbuck = (N + BNODES - 1) >> BSHIFT;   // 782
    const int chunk = (E + PB - 1) / PB;            // 25000
    const int n2 = PB * nbuck;                      // 50048
    const int nb2 = (n2 + 255) / 256;               // 196

    // workspace carve-up (4-byte elems)
    int*   hist   = (int*)d_ws;                   // PB*nbuck
    int*   offs   = hist + n2;                    // PB*nbuck
    int*   bsums  = offs + n2;                    // 256
    int*   btot   = bsums + 256;                  // nbuck
    int*   bbase  = btot + nbuck;                 // nbuck+1
    int*   rowst  = bbase + nbuck + 1;            // N
    int*   rowend = rowst + N;                    // N
    float* dinv   = (float*)(rowend + N);         // N
    int*   col    = (int*)(dinv + N);             // E
    float* P      = (float*)(col + E);            // N*128 f32 worth
    float* Q      = P + (long)N * 128;            // N*128 f32 worth

    __half*   msgX  = (__half*)P;     // N x 64 f16
    unsigned* ebuf  = (unsigned*)Q;   // E x 4B (dead before aggX written)
    float*    aggX  = Q;              // N x 64 f32
    __half*   msg1  = (__half*)P;     // N x 128 f16
    float*    aggH1 = Q;              // N x 128 f32
    float*    h2    = P;              // N x 128 f32
    __half*   msg3  = (__half*)Q;     // N x 64 f16

    const int gb = (N + BR - 1) / BR;

    // ---- CSR build (block-private counting sort) ----
    hipMemsetAsync(btot, 0, (size_t)nbuck * sizeof(int), stream);
    phist_k<<<PB, 256, 0, stream>>>(dst, hist, btot, E, nbuck, chunk);
    scan_blocks_k<<<nb2, 256, 0, stream>>>(hist, offs, bsums, n2);
    scan_sums_k<<<1, 512, 0, stream>>>(bsums, nb2);
    finish_offs_k<<<nb2, 256, 0, stream>>>(offs, bsums, n2);
    bbase_scan_k<<<1, 1024, 0, stream>>>(btot, bbase, nbuck, E);
    part2_k<<<PB, 256, 0, stream>>>(src, dst, offs, ebuf, E, nbuck, chunk);
    finalize_k<<<nbuck, 256, 0, stream>>>(ebuf, hist, offs, bbase, nbuck,
                                          rowst, rowend, dinv, col, x, msgX, N);

    // ---- layer 1: aggregate x at 64, then GEMM 64->128 ----
    agg_f16_k<64, false><<<(N + 31) / 32, 256, 0, stream>>>(msgX, rowst, rowend, col,
                                                            dinv, nullptr, aggX, N);
    gemm_k<64, 128, true, true, true><<<gb, 256, 0, stream>>>(aggX, W1, b1, dinv,
                                                              (void*)msg1, N);

    // ---- layer 2: aggregate msg1 at 128, then GEMM 128->128 ----
    agg_f16_k<128, false><<<(N + 15) / 16, 256, 0, stream>>>(msg1, rowst, rowend, col,
                                                             dinv, nullptr, aggH1, N);
    gemm_k<128, 128, true, true, false><<<gb, 256, 0, stream>>>(aggH1, W2, b2, nullptr,
                                                                (void*)h2, N);

    // ---- layer 3: GEMM 128->64 (emit f16 msg), aggregate at 64 -> out ----
    gemm_k<128, 64, false, false, true><<<gb, 256, 0, stream>>>(h2, W3, nullptr, dinv,
                                                                (void*)msg3, N);
    agg_f16_k<64, true><<<(N + 31) / 32, 256, 0, stream>>>(msg3, rowst, rowend, col,
                                                           dinv, b3, out, N);
}

// Round 6
// 446.676 us; speedup vs baseline: 15.5449x; 1.2023x over previous
//
#include <hip/hip_runtime.h>
#include <hip/hip_bf16.h>
#include <hip/hip_fp16.h>

// ---------------------------------------------------------------------------
// GCN 3-layer forward. N=100000, E=1600000, F: 64 -> 128 -> 128 -> 64.
// R6: MFMA f16 GEMMs (swizzled-W LDS, fused epilogues) + f16 agg outputs
//     + 4x-unrolled gather. CSR build unchanged from R5 (block-private sort).
// Pipeline:
//   CSR: phist -> scans -> part2 -> finalize (rowst/rowend/dinv/col + msgX f16)
//   wprep: W1/W2/W3 f32 -> f16 in MFMA B-fragment order
//   agg1(64,f16) -> gemm1(64->128,+b1,relu,*dinv -> f16)
//   agg2(128,f16) -> gemm2(128->128,+b2,relu -> f16)
//   gemm3(128->64,*dinv -> f16) -> agg3(64,+b3 -> f32 out)
// ---------------------------------------------------------------------------

typedef _Float16 h8 __attribute__((ext_vector_type(8)));
typedef float f4 __attribute__((ext_vector_type(4)));

constexpr int BSHIFT = 7;                 // 128 nodes per bucket
constexpr int BNODES = 1 << BSHIFT;
constexpr int PB     = 64;                // partition blocks
constexpr int CAP    = 4096;              // finalize LDS stage capacity

// ---- f16 helpers ----------------------------------------------------------
__device__ inline void load8h(const _Float16* p, float* f) {
    h8 v = *(const h8*)p;
#pragma unroll
    for (int j = 0; j < 8; j++) f[j] = (float)v[j];
}

__device__ inline void store8h(_Float16* p, const float* f) {
    h8 v;
#pragma unroll
    for (int j = 0; j < 8; j++) v[j] = (_Float16)f[j];
    *(h8*)p = v;
}

__device__ inline void store4h(_Float16* p, float4 v) {
    _Float16 t[4] = {(_Float16)v.x, (_Float16)v.y, (_Float16)v.z, (_Float16)v.w};
    *(uint2*)p = *(uint2*)t;
}

// ---- CSR build (unchanged from R5) ----------------------------------------
__global__ __launch_bounds__(256) void phist_k(const int* __restrict__ dst,
                                               int* __restrict__ hist,
                                               int* __restrict__ btot,
                                               int E, int nbuck, int chunk) {
    __shared__ int h[1024];
    for (int i = threadIdx.x; i < nbuck; i += 256) h[i] = 0;
    __syncthreads();
    int beg = blockIdx.x * chunk;
    int end = min(E, beg + chunk);
    for (int e = beg + threadIdx.x; e < end; e += 256)
        atomicAdd(&h[dst[e] >> BSHIFT], 1);
    __syncthreads();
    for (int i = threadIdx.x; i < nbuck; i += 256) {
        int v = h[i];
        hist[(long)blockIdx.x * nbuck + i] = v;
        if (v) atomicAdd(&btot[i], v);
    }
}

__global__ __launch_bounds__(256) void scan_blocks_k(const int* __restrict__ in,
                                                     int* __restrict__ excl,
                                                     int* __restrict__ bsums, int n) {
    __shared__ int s[256];
    int tid = threadIdx.x;
    int i = blockIdx.x * 256 + tid;
    int v = (i < n) ? in[i] : 0;
    s[tid] = v;
    __syncthreads();
    for (int off = 1; off < 256; off <<= 1) {
        int t = (tid >= off) ? s[tid - off] : 0;
        __syncthreads();
        s[tid] += t;
        __syncthreads();
    }
    if (i < n) excl[i] = s[tid] - v;
    if (tid == 255) bsums[blockIdx.x] = s[255];
}

__global__ __launch_bounds__(512) void scan_sums_k(int* bsums, int nb) {
    __shared__ int s[512];
    int tid = threadIdx.x;
    int v = (tid < nb) ? bsums[tid] : 0;
    s[tid] = v;
    __syncthreads();
    for (int off = 1; off < 512; off <<= 1) {
        int t = (tid >= off) ? s[tid - off] : 0;
        __syncthreads();
        s[tid] += t;
        __syncthreads();
    }
    if (tid < nb) bsums[tid] = s[tid] - v;
}

__global__ __launch_bounds__(256) void finish_offs_k(int* __restrict__ offs,
                                                     const int* __restrict__ bsums,
                                                     int n) {
    int i = blockIdx.x * 256 + threadIdx.x;
    if (i < n) offs[i] += bsums[blockIdx.x];
}

__global__ __launch_bounds__(1024) void bbase_scan_k(const int* __restrict__ btot,
                                                     int* __restrict__ bbase,
                                                     int nbuck, int E) {
    __shared__ int s[1024];
    int tid = threadIdx.x;
    int v = (tid < nbuck) ? btot[tid] : 0;
    s[tid] = v;
    __syncthreads();
    for (int off = 1; off < 1024; off <<= 1) {
        int t = (tid >= off) ? s[tid - off] : 0;
        __syncthreads();
        s[tid] += t;
        __syncthreads();
    }
    if (tid < nbuck) bbase[tid] = s[tid] - v;
    if (tid == 0) bbase[nbuck] = E;
}

__global__ __launch_bounds__(256) void part2_k(const int* __restrict__ src,
                                               const int* __restrict__ dst,
                                               const int* __restrict__ offs,
                                               unsigned* __restrict__ ebuf,
                                               int E, int nbuck, int chunk) {
    __shared__ int cur[1024];
    for (int i = threadIdx.x; i < nbuck; i += 256)
        cur[i] = offs[(long)blockIdx.x * nbuck + i];
    __syncthreads();
    int beg = blockIdx.x * chunk;
    int end = min(E, beg + chunk);
    for (int e = beg + threadIdx.x; e < end; e += 256) {
        int d = dst[e];
        int b = d >> BSHIFT;
        int pos = atomicAdd(&cur[b], 1);
        ebuf[pos] = ((unsigned)(d & (BNODES - 1)) << 25) | (unsigned)src[e];
    }
}

__global__ __launch_bounds__(256) void finalize_k(const unsigned* __restrict__ ebuf,
                                                  const int* __restrict__ hist,
                                                  const int* __restrict__ offs,
                                                  const int* __restrict__ bbase,
                                                  int nbuck,
                                                  int* __restrict__ rowst,
                                                  int* __restrict__ rowend,
                                                  float* __restrict__ dinv,
                                                  int* __restrict__ col,
                                                  const float* __restrict__ x,
                                                  _Float16* __restrict__ msgX, int N) {
    __shared__ unsigned se[CAP];
    __shared__ int cj[PB], sj[PB], sb[PB];
    __shared__ int cnt_s[BNODES], scan_s[BNODES], cur_s[BNODES];
    __shared__ float di_s[BNODES];
    __shared__ int m_s;

    int b = blockIdx.x, tid = threadIdx.x;
    int node0 = b << BSHIFT;
    int nn = min(BNODES, N - node0);
    int beg = bbase[b];

    if (tid < PB) {
        cj[tid] = hist[(long)tid * nbuck + b];
        sj[tid] = offs[(long)tid * nbuck + b];
    }
    if (tid < BNODES) cnt_s[tid] = 0;
    __syncthreads();

    if (tid < PB) sb[tid] = cj[tid];
    __syncthreads();
    for (int off = 1; off < PB; off <<= 1) {
        int t = 0;
        if (tid < PB && tid >= off) t = sb[tid - off];
        __syncthreads();
        if (tid < PB) sb[tid] += t;
        __syncthreads();
    }
    if (tid == PB - 1) m_s = sb[PB - 1];
    __syncthreads();
    int m = m_s;

    {
        int j = tid >> 2, lane = tid & 3;
        int base = sb[j] - cj[j], c = cj[j], s0 = sj[j];
        for (int k = lane; k < c; k += 4) {
            unsigned e = ebuf[s0 + k];
            int idx = base + k;
            if (idx < CAP) se[idx] = e;
            else atomicAdd(&cnt_s[e >> 25], 1);
        }
    }
    __syncthreads();

    int mcap = m < CAP ? m : CAP;
    for (int i = tid; i < mcap; i += 256) atomicAdd(&cnt_s[se[i] >> 25], 1);
    __syncthreads();

    int v = (tid < BNODES) ? cnt_s[tid] : 0;
    if (tid < BNODES) scan_s[tid] = v;
    __syncthreads();
    for (int off = 1; off < BNODES; off <<= 1) {
        int t = 0;
        if (tid < BNODES && tid >= off) t = scan_s[tid - off];
        __syncthreads();
        if (tid < BNODES) scan_s[tid] += t;
        __syncthreads();
    }
    if (tid < nn) {
        int ex = scan_s[tid] - v;
        int st = beg + ex;
        rowst[node0 + tid] = st;
        rowend[node0 + tid] = st + v;
        float di = rsqrtf((float)v + 1.0f);
        dinv[node0 + tid] = di;
        di_s[tid] = di;
        cur_s[tid] = ex;
    }
    __syncthreads();

    for (int i = tid; i < mcap; i += 256) {
        unsigned e = se[i];
        int p = atomicAdd(&cur_s[e >> 25], 1);
        col[beg + p] = (int)(e & 0x1FFFFFFu);
    }
    if (m > CAP) {
        int j = tid >> 2, lane = tid & 3;
        int base = sb[j] - cj[j], c = cj[j], s0 = sj[j];
        for (int k = lane; k < c; k += 4) {
            int idx = base + k;
            if (idx >= CAP) {
                unsigned e = ebuf[s0 + k];
                int p = atomicAdd(&cur_s[e >> 25], 1);
                col[beg + p] = (int)(e & 0x1FFFFFFu);
            }
        }
    }

    // fused msgX prep: msgX[n,64] f16 = dinv[n] * x[n,:]
    for (int t = tid; t < nn * 16; t += 256) {
        int nl = t >> 4, q = t & 15;
        int node = node0 + nl;
        float4 vx = *(const float4*)(x + (long)node * 64 + q * 4);
        float di = di_s[nl];
        vx.x *= di; vx.y *= di; vx.z *= di; vx.w *= di;
        store4h(msgX + (long)node * 64 + q * 4, vx);
    }
}

// ---- aggregation ----------------------------------------------------------
// acc = msg[n,:] + sum_e msg[col[e],:]; out = F16OUT ? f16(dinv*acc)
//                                            : f32(bias + dinv*acc)
template <int F, bool BIAS, bool F16OUT>
__global__ __launch_bounds__(256) void agg_f16_k(const _Float16* __restrict__ msg,
                                                 const int* __restrict__ rowst,
                                                 const int* __restrict__ rowend,
                                                 const int* __restrict__ col,
                                                 const float* __restrict__ dinv,
                                                 const float* __restrict__ b,
                                                 void* __restrict__ out, int n) {
    constexpr int LPN = F / 8;       // lanes per node (16B per lane)
    constexpr int NPB = 256 / LPN;
    int node = blockIdx.x * NPB + threadIdx.x / LPN;
    int q = threadIdx.x % LPN;
    if (node >= n) return;

    float acc[8];
    load8h(msg + (long)node * F + q * 8, acc);  // self term (dinv folded)

    int beg = rowst[node], end = rowend[node];
    int e = beg;
    for (; e + 4 <= end; e += 4) {   // 4 independent gathers in flight
        int s0 = col[e], s1 = col[e + 1], s2 = col[e + 2], s3 = col[e + 3];
        float v0[8], v1[8], v2[8], v3[8];
        load8h(msg + (long)s0 * F + q * 8, v0);
        load8h(msg + (long)s1 * F + q * 8, v1);
        load8h(msg + (long)s2 * F + q * 8, v2);
        load8h(msg + (long)s3 * F + q * 8, v3);
#pragma unroll
        for (int j = 0; j < 8; j++) acc[j] += (v0[j] + v1[j]) + (v2[j] + v3[j]);
    }
    for (; e < end; e++) {
        int s = col[e];
        float v[8];
        load8h(msg + (long)s * F + q * 8, v);
#pragma unroll
        for (int j = 0; j < 8; j++) acc[j] += v[j];
    }

    float di = dinv[node];
    float o[8];
#pragma unroll
    for (int j = 0; j < 8; j++) o[j] = di * acc[j];
    if (BIAS) {
#pragma unroll
        for (int j = 0; j < 8; j++) o[j] += b[q * 8 + j];
    }
    if (F16OUT) {
        store8h((_Float16*)out + (long)node * F + q * 8, o);
    } else {
        float* dst = (float*)out + (long)node * F + q * 8;
        *(float4*)dst = make_float4(o[0], o[1], o[2], o[3]);
        *(float4*)(dst + 4) = make_float4(o[4], o[5], o[6], o[7]);
    }
}

// ---- MFMA dense transform -------------------------------------------------
// wprep: W[K][FOUT] f32 -> f16 in B-fragment order:
//   Wsw[((chunk*NT + tile)*64 + lane)*8 + j] = W[chunk*32 + (lane>>4)*8 + j][tile*16 + (lane&15)]
template <int K, int FOUT>
__global__ __launch_bounds__(256) void wprep_k(const float* __restrict__ W,
                                               _Float16* __restrict__ Wsw) {
    constexpr int NT = FOUT / 16;
    int t = blockIdx.x * 256 + threadIdx.x;
    if (t >= (K / 32) * NT * 64) return;
    int lane = t & 63;
    int tile = (t >> 6) % NT;
    int chunk = (t >> 6) / NT;
    int kbase = chunk * 32 + (lane >> 4) * 8;
    int nc = tile * 16 + (lane & 15);
    h8 v;
#pragma unroll
    for (int j = 0; j < 8; j++) v[j] = (_Float16)W[(kbase + j) * FOUT + nc];
    ((h8*)Wsw)[t] = v;
}

// C[n,FOUT] f16 = epi(A[n,K] f16 @ W); epi: +bias, relu, *dinv[row]
// block = 256 (4 waves), 64 rows/block; per wave one 16-row tile.
template <int K, int FOUT, bool BIAS, bool RELU, bool DINV>
__global__ __launch_bounds__(256) void gemm_mfma_k(const _Float16* __restrict__ A,
                                                   const _Float16* __restrict__ Wsw,
                                                   const float* __restrict__ bias,
                                                   const float* __restrict__ dinv,
                                                   _Float16* __restrict__ C, int n) {
    constexpr int NT = FOUT / 16;   // 16-col tiles
    constexpr int NC = K / 32;      // 32-deep K chunks
    __shared__ _Float16 wl[K * FOUT];

    int tid = threadIdx.x;
    for (int i = tid; i < K * FOUT / 8; i += 256)
        ((h8*)wl)[i] = ((const h8*)Wsw)[i];
    __syncthreads();

    int lane = tid & 63, wave = tid >> 6;
    int quad = lane >> 4, cl = lane & 15;
    int row0 = blockIdx.x * 64 + wave * 16;

    // A fragments: A[m=cl][k=quad*8+j], chunk-strided
    h8 a[NC];
    const _Float16* arow = A + (long)(row0 + cl) * K + quad * 8;
#pragma unroll
    for (int c = 0; c < NC; c++) a[c] = *(const h8*)(arow + c * 32);

    f4 acc[NT];
#pragma unroll
    for (int t = 0; t < NT; t++) acc[t] = (f4){0.f, 0.f, 0.f, 0.f};

    const h8* wv = (const h8*)wl;
#pragma unroll
    for (int c = 0; c < NC; c++) {
#pragma unroll
        for (int t = 0; t < NT; t++)
            acc[t] = __builtin_amdgcn_mfma_f32_16x16x32_f16(
                a[c], wv[(c * NT + t) * 64 + lane], acc[t], 0, 0, 0);
    }

    // C/D layout: col = lane&15 (tile*16+cl), row = quad*4 + reg
#pragma unroll
    for (int t = 0; t < NT; t++) {
        int c0 = t * 16 + cl;
        float bb = BIAS ? bias[c0] : 0.f;
#pragma unroll
        for (int r = 0; r < 4; r++) {
            int row = row0 + quad * 4 + r;
            if (row >= n) continue;
            float v = acc[t][r] + bb;
            if (RELU) v = fmaxf(v, 0.f);
            if (DINV) v *= dinv[row];
            C[(long)row * FOUT + c0] = (_Float16)v;
        }
    }
}

extern "C" void kernel_launch(void* const* d_in, const int* in_sizes, int n_in,
                              void* d_out, int out_size, void* d_ws, size_t ws_size,
                              hipStream_t stream) {
    const float* x  = (const float*)d_in[0];
    const int*   ei = (const int*)d_in[1];
    const float* W1 = (const float*)d_in[2];
    const float* b1 = (const float*)d_in[3];
    const float* W2 = (const float*)d_in[4];
    const float* b2 = (const float*)d_in[5];
    const float* W3 = (const float*)d_in[6];
    const float* b3 = (const float*)d_in[7];
    float* out = (float*)d_out;

    const int N = in_sizes[0] / 64;
    const int E = in_sizes[1] / 2;
    const int* src = ei;
    const int* dst = ei + E;
    const int nbuck = (N + BNODES - 1) >> BSHIFT;   // 782
    const int chunk = (E + PB - 1) / PB;            // 25000
    const int n2 = PB * nbuck;                      // 50048
    const int nb2 = (n2 + 255) / 256;

    // workspace carve-up (4-byte elems)
    int*   hist   = (int*)d_ws;                   // PB*nbuck
    int*   offs   = hist + n2;                    // PB*nbuck
    int*   bsums  = offs + n2;                    // 256
    int*   btot   = bsums + 256;                  // nbuck
    int*   bbase  = btot + nbuck;                 // nbuck+1
    int*   rowst  = bbase + nbuck + 1;            // N
    int*   rowend = rowst + N;                    // N
    float* dinv   = (float*)(rowend + N);         // N
    int*   col    = (int*)(dinv + N);             // E
    _Float16* w1s = (_Float16*)(col + E);         // 64*128 f16
    _Float16* w2s = w1s + 64 * 128;               // 128*128 f16
    _Float16* w3s = w2s + 128 * 128;              // 128*64 f16
    float* P      = (float*)(w3s + 128 * 64);     // N*128 f32 worth
    float* Q      = P + (long)N * 128;            // N*128 f32 worth

    _Float16* msgX  = (_Float16*)P;   // N x 64 f16
    unsigned* ebuf  = (unsigned*)Q;   // E x 4B (dead before aggX written)
    _Float16* aggX  = (_Float16*)Q;   // N x 64 f16
    _Float16* msg1  = (_Float16*)P;   // N x 128 f16
    _Float16* aggH1 = (_Float16*)Q;   // N x 128 f16
    _Float16* h2    = (_Float16*)P;   // N x 128 f16
    _Float16* msg3  = (_Float16*)Q;   // N x 64 f16

    const int gb = (N + 63) / 64;     // 1563 MFMA gemm blocks

    // ---- weight swizzle (independent of graph) ----
    wprep_k<64, 128><<<(64 * 128 / 8 + 255) / 256, 256, 0, stream>>>(W1, w1s);
    wprep_k<128, 128><<<(128 * 128 / 8 + 255) / 256, 256, 0, stream>>>(W2, w2s);
    wprep_k<128, 64><<<(128 * 64 / 8 + 255) / 256, 256, 0, stream>>>(W3, w3s);

    // ---- CSR build (block-private counting sort) ----
    hipMemsetAsync(btot, 0, (size_t)nbuck * sizeof(int), stream);
    phist_k<<<PB, 256, 0, stream>>>(dst, hist, btot, E, nbuck, chunk);
    scan_blocks_k<<<nb2, 256, 0, stream>>>(hist, offs, bsums, n2);
    scan_sums_k<<<1, 512, 0, stream>>>(bsums, nb2);
    finish_offs_k<<<nb2, 256, 0, stream>>>(offs, bsums, n2);
    bbase_scan_k<<<1, 1024, 0, stream>>>(btot, bbase, nbuck, E);
    part2_k<<<PB, 256, 0, stream>>>(src, dst, offs, ebuf, E, nbuck, chunk);
    finalize_k<<<nbuck, 256, 0, stream>>>(ebuf, hist, offs, bbase, nbuck,
                                          rowst, rowend, dinv, col, x, msgX, N);

    // ---- layer 1 ----
    agg_f16_k<64, false, true><<<(N + 31) / 32, 256, 0, stream>>>(
        msgX, rowst, rowend, col, dinv, nullptr, (void*)aggX, N);
    gemm_mfma_k<64, 128, true, true, true><<<gb, 256, 0, stream>>>(
        aggX, w1s, b1, dinv, msg1, N);

    // ---- layer 2 ----
    agg_f16_k<128, false, true><<<(N + 15) / 16, 256, 0, stream>>>(
        msg1, rowst, rowend, col, dinv, nullptr, (void*)aggH1, N);
    gemm_mfma_k<128, 128, true, true, false><<<gb, 256, 0, stream>>>(
        aggH1, w2s, b2, nullptr, h2, N);

    // ---- layer 3 ----
    gemm_mfma_k<128, 64, false, false, true><<<gb, 256, 0, stream>>>(
        h2, w3s, nullptr, dinv, msg3, N);
    agg_f16_k<64, true, false><<<(N + 31) / 32, 256, 0, stream>>>(
        msg3, rowst, rowend, col, dinv, b3, (void*)out, N);
}

// Round 7
// 403.733 us; speedup vs baseline: 17.1983x; 1.1064x over previous
//
#include <hip/hip_runtime.h>
#include <hip/hip_bf16.h>
#include <hip/hip_fp16.h>

// ---------------------------------------------------------------------------
// GCN 3-layer forward. N=100000, E=1600000, F: 64 -> 128 -> 128 -> 64.
// R7: PB 64 -> 256 (part2/phist were 2.5%-occupancy latency-bound).
//   CSR: phist -> scans -> part2 -> finalize (rowst/rowend/dinv/col + msgX f16)
//   wprep: W1/W2/W3 f32 -> f16 in MFMA B-fragment order
//   agg1(64,f16) -> gemm1(64->128,+b1,relu,*dinv -> f16)
//   agg2(128,f16) -> gemm2(128->128,+b2,relu -> f16)
//   gemm3(128->64,*dinv -> f16) -> agg3(64,+b3 -> f32 out)
// ---------------------------------------------------------------------------

typedef _Float16 h8 __attribute__((ext_vector_type(8)));
typedef float f4 __attribute__((ext_vector_type(4)));

constexpr int BSHIFT = 7;                 // 128 nodes per bucket
constexpr int BNODES = 1 << BSHIFT;
constexpr int PB     = 256;               // partition blocks (1 per CU)
constexpr int CAP    = 4096;              // finalize LDS stage capacity

// ---- f16 helpers ----------------------------------------------------------
__device__ inline void load8h(const _Float16* p, float* f) {
    h8 v = *(const h8*)p;
#pragma unroll
    for (int j = 0; j < 8; j++) f[j] = (float)v[j];
}

__device__ inline void store8h(_Float16* p, const float* f) {
    h8 v;
#pragma unroll
    for (int j = 0; j < 8; j++) v[j] = (_Float16)f[j];
    *(h8*)p = v;
}

__device__ inline void store4h(_Float16* p, float4 v) {
    _Float16 t[4] = {(_Float16)v.x, (_Float16)v.y, (_Float16)v.z, (_Float16)v.w};
    *(uint2*)p = *(uint2*)t;
}

// ---- CSR build ------------------------------------------------------------
__global__ __launch_bounds__(256) void phist_k(const int* __restrict__ dst,
                                               int* __restrict__ hist,
                                               int* __restrict__ btot,
                                               int E, int nbuck, int chunk) {
    __shared__ int h[1024];
    for (int i = threadIdx.x; i < nbuck; i += 256) h[i] = 0;
    __syncthreads();
    int beg = blockIdx.x * chunk;
    int end = min(E, beg + chunk);
    for (int e = beg + threadIdx.x; e < end; e += 256)
        atomicAdd(&h[dst[e] >> BSHIFT], 1);
    __syncthreads();
    for (int i = threadIdx.x; i < nbuck; i += 256) {
        int v = h[i];
        hist[(long)blockIdx.x * nbuck + i] = v;
        if (v) atomicAdd(&btot[i], v);
    }
}

__global__ __launch_bounds__(256) void scan_blocks_k(const int* __restrict__ in,
                                                     int* __restrict__ excl,
                                                     int* __restrict__ bsums, int n) {
    __shared__ int s[256];
    int tid = threadIdx.x;
    int i = blockIdx.x * 256 + tid;
    int v = (i < n) ? in[i] : 0;
    s[tid] = v;
    __syncthreads();
    for (int off = 1; off < 256; off <<= 1) {
        int t = (tid >= off) ? s[tid - off] : 0;
        __syncthreads();
        s[tid] += t;
        __syncthreads();
    }
    if (i < n) excl[i] = s[tid] - v;
    if (tid == 255) bsums[blockIdx.x] = s[255];
}

// 1 block, 1024 threads: exclusive scan of nb (<=1024) block sums
__global__ __launch_bounds__(1024) void scan_sums_k(int* bsums, int nb) {
    __shared__ int s[1024];
    int tid = threadIdx.x;
    int v = (tid < nb) ? bsums[tid] : 0;
    s[tid] = v;
    __syncthreads();
    for (int off = 1; off < 1024; off <<= 1) {
        int t = (tid >= off) ? s[tid - off] : 0;
        __syncthreads();
        s[tid] += t;
        __syncthreads();
    }
    if (tid < nb) bsums[tid] = s[tid] - v;
}

__global__ __launch_bounds__(256) void finish_offs_k(int* __restrict__ offs,
                                                     const int* __restrict__ bsums,
                                                     int n) {
    int i = blockIdx.x * 256 + threadIdx.x;
    if (i < n) offs[i] += bsums[blockIdx.x];
}

__global__ __launch_bounds__(1024) void bbase_scan_k(const int* __restrict__ btot,
                                                     int* __restrict__ bbase,
                                                     int nbuck, int E) {
    __shared__ int s[1024];
    int tid = threadIdx.x;
    int v = (tid < nbuck) ? btot[tid] : 0;
    s[tid] = v;
    __syncthreads();
    for (int off = 1; off < 1024; off <<= 1) {
        int t = (tid >= off) ? s[tid - off] : 0;
        __syncthreads();
        s[tid] += t;
        __syncthreads();
    }
    if (tid < nbuck) bbase[tid] = s[tid] - v;
    if (tid == 0) bbase[nbuck] = E;
}

__global__ __launch_bounds__(256) void part2_k(const int* __restrict__ src,
                                               const int* __restrict__ dst,
                                               const int* __restrict__ offs,
                                               unsigned* __restrict__ ebuf,
                                               int E, int nbuck, int chunk) {
    __shared__ int cur[1024];
    for (int i = threadIdx.x; i < nbuck; i += 256)
        cur[i] = offs[(long)blockIdx.x * nbuck + i];
    __syncthreads();
    int beg = blockIdx.x * chunk;
    int end = min(E, beg + chunk);
    for (int e = beg + threadIdx.x; e < end; e += 256) {
        int d = dst[e];
        int b = d >> BSHIFT;
        int pos = atomicAdd(&cur[b], 1);
        ebuf[pos] = ((unsigned)(d & (BNODES - 1)) << 25) | (unsigned)src[e];
    }
}

// block-per-bucket: gather PB segments -> LDS; count/scan/place; dinv; msgX
__global__ __launch_bounds__(256) void finalize_k(const unsigned* __restrict__ ebuf,
                                                  const int* __restrict__ hist,
                                                  const int* __restrict__ offs,
                                                  const int* __restrict__ bbase,
                                                  int nbuck,
                                                  int* __restrict__ rowst,
                                                  int* __restrict__ rowend,
                                                  float* __restrict__ dinv,
                                                  int* __restrict__ col,
                                                  const float* __restrict__ x,
                                                  _Float16* __restrict__ msgX, int N) {
    __shared__ unsigned se[CAP];
    __shared__ int cj[PB], sj[PB], sb[PB];
    __shared__ int cnt_s[BNODES], scan_s[BNODES], cur_s[BNODES];
    __shared__ float di_s[BNODES];

    int b = blockIdx.x, tid = threadIdx.x;
    int node0 = b << BSHIFT;
    int nn = min(BNODES, N - node0);
    int beg = bbase[b];

    if (tid < PB) {
        cj[tid] = hist[(long)tid * nbuck + b];
        sj[tid] = offs[(long)tid * nbuck + b];
    }
    if (tid < BNODES) cnt_s[tid] = 0;
    __syncthreads();

    // exclusive bases of the PB segments within this bucket (inclusive scan cj)
    if (tid < PB) sb[tid] = cj[tid];
    __syncthreads();
    for (int off = 1; off < PB; off <<= 1) {
        int t = 0;
        if (tid < PB && tid >= off) t = sb[tid - off];
        __syncthreads();
        if (tid < PB) sb[tid] += t;
        __syncthreads();
    }
    int m = sb[PB - 1];
    __syncthreads();

    // gather segments into LDS: 1 thread per segment (~8 edges each)
    {
        int j = tid;
        int base = sb[j] - cj[j], c = cj[j], s0 = sj[j];
        for (int k = 0; k < c; k++) {
            unsigned e = ebuf[s0 + k];
            int idx = base + k;
            if (idx < CAP) se[idx] = e;
            else atomicAdd(&cnt_s[e >> 25], 1);  // overflow: count directly
        }
    }
    __syncthreads();

    int mcap = m < CAP ? m : CAP;
    for (int i = tid; i < mcap; i += 256) atomicAdd(&cnt_s[se[i] >> 25], 1);
    __syncthreads();

    int v = (tid < BNODES) ? cnt_s[tid] : 0;
    if (tid < BNODES) scan_s[tid] = v;
    __syncthreads();
    for (int off = 1; off < BNODES; off <<= 1) {
        int t = 0;
        if (tid < BNODES && tid >= off) t = scan_s[tid - off];
        __syncthreads();
        if (tid < BNODES) scan_s[tid] += t;
        __syncthreads();
    }
    if (tid < nn) {
        int ex = scan_s[tid] - v;
        int st = beg + ex;
        rowst[node0 + tid] = st;
        rowend[node0 + tid] = st + v;
        float di = rsqrtf((float)v + 1.0f);
        dinv[node0 + tid] = di;
        di_s[tid] = di;
        cur_s[tid] = ex;
    }
    __syncthreads();

    for (int i = tid; i < mcap; i += 256) {
        unsigned e = se[i];
        int p = atomicAdd(&cur_s[e >> 25], 1);
        col[beg + p] = (int)(e & 0x1FFFFFFu);
    }
    if (m > CAP) {  // overflow spill (statistically never)
        int j = tid;
        int base = sb[j] - cj[j], c = cj[j], s0 = sj[j];
        for (int k = 0; k < c; k++) {
            int idx = base + k;
            if (idx >= CAP) {
                unsigned e = ebuf[s0 + k];
                int p = atomicAdd(&cur_s[e >> 25], 1);
                col[beg + p] = (int)(e & 0x1FFFFFFu);
            }
        }
    }

    // fused msgX prep: msgX[n,64] f16 = dinv[n] * x[n,:]
    for (int t = tid; t < nn * 16; t += 256) {
        int nl = t >> 4, q = t & 15;
        int node = node0 + nl;
        float4 vx = *(const float4*)(x + (long)node * 64 + q * 4);
        float di = di_s[nl];
        vx.x *= di; vx.y *= di; vx.z *= di; vx.w *= di;
        store4h(msgX + (long)node * 64 + q * 4, vx);
    }
}

// ---- aggregation ----------------------------------------------------------
template <int F, bool BIAS, bool F16OUT>
__global__ __launch_bounds__(256) void agg_f16_k(const _Float16* __restrict__ msg,
                                                 const int* __restrict__ rowst,
                                                 const int* __restrict__ rowend,
                                                 const int* __restrict__ col,
                                                 const float* __restrict__ dinv,
                                                 const float* __restrict__ b,
                                                 void* __restrict__ out, int n) {
    constexpr int LPN = F / 8;
    constexpr int NPB = 256 / LPN;
    int node = blockIdx.x * NPB + threadIdx.x / LPN;
    int q = threadIdx.x % LPN;
    if (node >= n) return;

    float acc[8];
    load8h(msg + (long)node * F + q * 8, acc);  // self term (dinv folded)

    int beg = rowst[node], end = rowend[node];
    int e = beg;
    for (; e + 4 <= end; e += 4) {
        int s0 = col[e], s1 = col[e + 1], s2 = col[e + 2], s3 = col[e + 3];
        float v0[8], v1[8], v2[8], v3[8];
        load8h(msg + (long)s0 * F + q * 8, v0);
        load8h(msg + (long)s1 * F + q * 8, v1);
        load8h(msg + (long)s2 * F + q * 8, v2);
        load8h(msg + (long)s3 * F + q * 8, v3);
#pragma unroll
        for (int j = 0; j < 8; j++) acc[j] += (v0[j] + v1[j]) + (v2[j] + v3[j]);
    }
    for (; e < end; e++) {
        int s = col[e];
        float v[8];
        load8h(msg + (long)s * F + q * 8, v);
#pragma unroll
        for (int j = 0; j < 8; j++) acc[j] += v[j];
    }

    float di = dinv[node];
    float o[8];
#pragma unroll
    for (int j = 0; j < 8; j++) o[j] = di * acc[j];
    if (BIAS) {
#pragma unroll
        for (int j = 0; j < 8; j++) o[j] += b[q * 8 + j];
    }
    if (F16OUT) {
        store8h((_Float16*)out + (long)node * F + q * 8, o);
    } else {
        float* dst = (float*)out + (long)node * F + q * 8;
        *(float4*)dst = make_float4(o[0], o[1], o[2], o[3]);
        *(float4*)(dst + 4) = make_float4(o[4], o[5], o[6], o[7]);
    }
}

// ---- MFMA dense transform -------------------------------------------------
template <int K, int FOUT>
__global__ __launch_bounds__(256) void wprep_k(const float* __restrict__ W,
                                               _Float16* __restrict__ Wsw) {
    constexpr int NT = FOUT / 16;
    int t = blockIdx.x * 256 + threadIdx.x;
    if (t >= (K / 32) * NT * 64) return;
    int lane = t & 63;
    int tile = (t >> 6) % NT;
    int chunk = (t >> 6) / NT;
    int kbase = chunk * 32 + (lane >> 4) * 8;
    int nc = tile * 16 + (lane & 15);
    h8 v;
#pragma unroll
    for (int j = 0; j < 8; j++) v[j] = (_Float16)W[(kbase + j) * FOUT + nc];
    ((h8*)Wsw)[t] = v;
}

template <int K, int FOUT, bool BIAS, bool RELU, bool DINV>
__global__ __launch_bounds__(256) void gemm_mfma_k(const _Float16* __restrict__ A,
                                                   const _Float16* __restrict__ Wsw,
                                                   const float* __restrict__ bias,
                                                   const float* __restrict__ dinv,
                                                   _Float16* __restrict__ C, int n) {
    constexpr int NT = FOUT / 16;
    constexpr int NC = K / 32;
    __shared__ _Float16 wl[K * FOUT];

    int tid = threadIdx.x;
    for (int i = tid; i < K * FOUT / 8; i += 256)
        ((h8*)wl)[i] = ((const h8*)Wsw)[i];
    __syncthreads();

    int lane = tid & 63, wave = tid >> 6;
    int quad = lane >> 4, cl = lane & 15;
    int row0 = blockIdx.x * 64 + wave * 16;

    h8 a[NC];
    const _Float16* arow = A + (long)(row0 + cl) * K + quad * 8;
#pragma unroll
    for (int c = 0; c < NC; c++) a[c] = *(const h8*)(arow + c * 32);

    f4 acc[NT];
#pragma unroll
    for (int t = 0; t < NT; t++) acc[t] = (f4){0.f, 0.f, 0.f, 0.f};

    const h8* wv = (const h8*)wl;
#pragma unroll
    for (int c = 0; c < NC; c++) {
#pragma unroll
        for (int t = 0; t < NT; t++)
            acc[t] = __builtin_amdgcn_mfma_f32_16x16x32_f16(
                a[c], wv[(c * NT + t) * 64 + lane], acc[t], 0, 0, 0);
    }

#pragma unroll
    for (int t = 0; t < NT; t++) {
        int c0 = t * 16 + cl;
        float bb = BIAS ? bias[c0] : 0.f;
#pragma unroll
        for (int r = 0; r < 4; r++) {
            int row = row0 + quad * 4 + r;
            if (row >= n) continue;
            float v = acc[t][r] + bb;
            if (RELU) v = fmaxf(v, 0.f);
            if (DINV) v *= dinv[row];
            C[(long)row * FOUT + c0] = (_Float16)v;
        }
    }
}

extern "C" void kernel_launch(void* const* d_in, const int* in_sizes, int n_in,
                              void* d_out, int out_size, void* d_ws, size_t ws_size,
                              hipStream_t stream) {
    const float* x  = (const float*)d_in[0];
    const int*   ei = (const int*)d_in[1];
    const float* W1 = (const float*)d_in[2];
    const float* b1 = (const float*)d_in[3];
    const float* W2 = (const float*)d_in[4];
    const float* b2 = (const float*)d_in[5];
    const float* W3 = (const float*)d_in[6];
    const float* b3 = (const float*)d_in[7];
    float* out = (float*)d_out;

    const int N = in_sizes[0] / 64;
    const int E = in_sizes[1] / 2;
    const int* src = ei;
    const int* dst = ei + E;
    const int nbuck = (N + BNODES - 1) >> BSHIFT;   // 782
    const int chunk = (E + PB - 1) / PB;            // 6250
    const int n2 = PB * nbuck;                      // 200192
    const int nb2 = (n2 + 255) / 256;               // 782

    // workspace carve-up (4-byte elems)
    int*   hist   = (int*)d_ws;                   // PB*nbuck
    int*   offs   = hist + n2;                    // PB*nbuck
    int*   bsums  = offs + n2;                    // 1024
    int*   btot   = bsums + 1024;                 // nbuck
    int*   bbase  = btot + nbuck;                 // nbuck+1
    int*   rowst  = bbase + nbuck + 1;            // N
    int*   rowend = rowst + N;                    // N
    float* dinv   = (float*)(rowend + N);         // N
    int*   col    = (int*)(dinv + N);             // E
    _Float16* w1s = (_Float16*)(col + E);         // 64*128 f16
    _Float16* w2s = w1s + 64 * 128;               // 128*128 f16
    _Float16* w3s = w2s + 128 * 128;              // 128*64 f16
    float* P      = (float*)(w3s + 128 * 64);     // N*128 f32 worth
    float* Q      = P + (long)N * 128;            // N*128 f32 worth

    _Float16* msgX  = (_Float16*)P;   // N x 64 f16
    unsigned* ebuf  = (unsigned*)Q;   // E x 4B (dead before aggX written)
    _Float16* aggX  = (_Float16*)Q;   // N x 64 f16
    _Float16* msg1  = (_Float16*)P;   // N x 128 f16
    _Float16* aggH1 = (_Float16*)Q;   // N x 128 f16
    _Float16* h2    = (_Float16*)P;   // N x 128 f16
    _Float16* msg3  = (_Float16*)Q;   // N x 64 f16

    const int gb = (N + 63) / 64;

    // ---- weight swizzle ----
    wprep_k<64, 128><<<(64 * 128 / 8 + 255) / 256, 256, 0, stream>>>(W1, w1s);
    wprep_k<128, 128><<<(128 * 128 / 8 + 255) / 256, 256, 0, stream>>>(W2, w2s);
    wprep_k<128, 64><<<(128 * 64 / 8 + 255) / 256, 256, 0, stream>>>(W3, w3s);

    // ---- CSR build (block-private counting sort) ----
    hipMemsetAsync(btot, 0, (size_t)nbuck * sizeof(int), stream);
    phist_k<<<PB, 256, 0, stream>>>(dst, hist, btot, E, nbuck, chunk);
    scan_blocks_k<<<nb2, 256, 0, stream>>>(hist, offs, bsums, n2);
    scan_sums_k<<<1, 1024, 0, stream>>>(bsums, nb2);
    finish_offs_k<<<nb2, 256, 0, stream>>>(offs, bsums, n2);
    bbase_scan_k<<<1, 1024, 0, stream>>>(btot, bbase, nbuck, E);
    part2_k<<<PB, 256, 0, stream>>>(src, dst, offs, ebuf, E, nbuck, chunk);
    finalize_k<<<nbuck, 256, 0, stream>>>(ebuf, hist, offs, bbase, nbuck,
                                          rowst, rowend, dinv, col, x, msgX, N);

    // ---- layer 1 ----
    agg_f16_k<64, false, true><<<(N + 31) / 32, 256, 0, stream>>>(
        msgX, rowst, rowend, col, dinv, nullptr, (void*)aggX, N);
    gemm_mfma_k<64, 128, true, true, true><<<gb, 256, 0, stream>>>(
        aggX, w1s, b1, dinv, msg1, N);

    // ---- layer 2 ----
    agg_f16_k<128, false, true><<<(N + 15) / 16, 256, 0, stream>>>(
        msg1, rowst, rowend, col, dinv, nullptr, (void*)aggH1, N);
    gemm_mfma_k<128, 128, true, true, false><<<gb, 256, 0, stream>>>(
        aggH1, w2s, b2, nullptr, h2, N);

    // ---- layer 3 ----
    gemm_mfma_k<128, 64, false, false, true><<<gb, 256, 0, stream>>>(
        h2, w3s, nullptr, dinv, msg3, N);
    agg_f16_k<64, true, false><<<(N + 31) / 32, 256, 0, stream>>>(
        msg3, rowst, rowend, col, dinv, b3, (void*)out, N);
}

// Round 8
// 391.343 us; speedup vs baseline: 17.7428x; 1.0317x over previous
//
#include <hip/hip_runtime.h>
#include <hip/hip_bf16.h>
#include <hip/hip_fp16.h>

// ---------------------------------------------------------------------------
// GCN 3-layer forward. N=100000, E=1600000, F: 64 -> 128 -> 128 -> 64.
// R8: fused agg+MFMA-GEMM per layer (gather -> LDS tile -> MFMA, GEMM hidden
//     under gather shadow) + streamlined CSR (no memset/finish_offs/btot
//     atomics; merged scans; one wprep).
//   CSR: phist -> scan_blocks -> mid(scan bsums | colsum+scan bbase)
//        -> part2 -> finalize (rowst/rowend/dinv/col + msgX f16)
//   F1: fag<64,128>  msgX(P) -> msg1(Q)   [+b1, relu, *dinv]
//   F2: fag<128,128> msg1(Q) -> h2(P)     [+b2, relu]
//   gemm3<128,64> h2(P) -> msg3(Q)        [*dinv]
//   agg3<64> msg3(Q) -> out (+b3, f32)
// ---------------------------------------------------------------------------

typedef _Float16 h8 __attribute__((ext_vector_type(8)));
typedef float f4 __attribute__((ext_vector_type(4)));

constexpr int BSHIFT = 7;                 // 128 nodes per bucket
constexpr int BNODES = 1 << BSHIFT;
constexpr int PB     = 256;               // partition blocks
constexpr int CAP    = 4096;              // finalize LDS stage capacity

// ---- f16 helpers ----------------------------------------------------------
__device__ inline void load8h(const _Float16* p, float* f) {
    h8 v = *(const h8*)p;
#pragma unroll
    for (int j = 0; j < 8; j++) f[j] = (float)v[j];
}

__device__ inline void store8h(_Float16* p, const float* f) {
    h8 v;
#pragma unroll
    for (int j = 0; j < 8; j++) v[j] = (_Float16)f[j];
    *(h8*)p = v;
}

__device__ inline void store4h(_Float16* p, float4 v) {
    _Float16 t[4] = {(_Float16)v.x, (_Float16)v.y, (_Float16)v.z, (_Float16)v.w};
    *(uint2*)p = *(uint2*)t;
}

// ---- CSR build ------------------------------------------------------------
__global__ __launch_bounds__(256) void phist_k(const int* __restrict__ dst,
                                               int* __restrict__ hist,
                                               int E, int nbuck, int chunk) {
    __shared__ int h[1024];
    for (int i = threadIdx.x; i < nbuck; i += 256) h[i] = 0;
    __syncthreads();
    int beg = blockIdx.x * chunk;
    int end = min(E, beg + chunk);
    for (int e = beg + threadIdx.x; e < end; e += 256)
        atomicAdd(&h[dst[e] >> BSHIFT], 1);
    __syncthreads();
    for (int i = threadIdx.x; i < nbuck; i += 256)
        hist[(long)blockIdx.x * nbuck + i] = h[i];
}

__global__ __launch_bounds__(256) void scan_blocks_k(const int* __restrict__ in,
                                                     int* __restrict__ excl,
                                                     int* __restrict__ bsums, int n) {
    __shared__ int s[256];
    int tid = threadIdx.x;
    int i = blockIdx.x * 256 + tid;
    int v = (i < n) ? in[i] : 0;
    s[tid] = v;
    __syncthreads();
    for (int off = 1; off < 256; off <<= 1) {
        int t = (tid >= off) ? s[tid - off] : 0;
        __syncthreads();
        s[tid] += t;
        __syncthreads();
    }
    if (i < n) excl[i] = s[tid] - v;
    if (tid == 255) bsums[blockIdx.x] = s[255];
}

// block 0: exclusive scan of bsums (nb <= 1024)
// block 1: btot[b] = sum_j hist[j][b]; exclusive scan -> bbase
__global__ __launch_bounds__(1024) void mid_k(int* __restrict__ bsums, int nb,
                                              const int* __restrict__ hist,
                                              int* __restrict__ bbase,
                                              int nbuck, int E) {
    __shared__ int s[1024];
    int tid = threadIdx.x;
    int v = 0;
    if (blockIdx.x == 0) {
        v = (tid < nb) ? bsums[tid] : 0;
    } else {
        if (tid < nbuck) {
            int t0 = 0, t1 = 0, t2 = 0, t3 = 0;
            for (int j = 0; j < PB; j += 4) {
                t0 += hist[(long)(j + 0) * nbuck + tid];
                t1 += hist[(long)(j + 1) * nbuck + tid];
                t2 += hist[(long)(j + 2) * nbuck + tid];
                t3 += hist[(long)(j + 3) * nbuck + tid];
            }
            v = (t0 + t1) + (t2 + t3);
        }
    }
    s[tid] = v;
    __syncthreads();
    for (int off = 1; off < 1024; off <<= 1) {
        int t = (tid >= off) ? s[tid - off] : 0;
        __syncthreads();
        s[tid] += t;
        __syncthreads();
    }
    if (blockIdx.x == 0) {
        if (tid < nb) bsums[tid] = s[tid] - v;
    } else {
        if (tid < nbuck) bbase[tid] = s[tid] - v;
        if (tid == 0) bbase[nbuck] = E;
    }
}

// block-private partition; per-(block,bucket) base = offs[flat] + bsums[flat>>8]
__global__ __launch_bounds__(256) void part2_k(const int* __restrict__ src,
                                               const int* __restrict__ dst,
                                               const int* __restrict__ offs,
                                               const int* __restrict__ bsums,
                                               unsigned* __restrict__ ebuf,
                                               int E, int nbuck, int chunk) {
    __shared__ int cur[1024];
    for (int i = threadIdx.x; i < nbuck; i += 256) {
        long flat = (long)blockIdx.x * nbuck + i;
        cur[i] = offs[flat] + bsums[flat >> 8];
    }
    __syncthreads();
    int beg = blockIdx.x * chunk;
    int end = min(E, beg + chunk);
    for (int e = beg + threadIdx.x; e < end; e += 256) {
        int d = dst[e];
        int b = d >> BSHIFT;
        int pos = atomicAdd(&cur[b], 1);
        ebuf[pos] = ((unsigned)(d & (BNODES - 1)) << 25) | (unsigned)src[e];
    }
}

// block-per-bucket: gather PB segments -> LDS; count/scan/place; dinv; msgX
__global__ __launch_bounds__(256) void finalize_k(const unsigned* __restrict__ ebuf,
                                                  const int* __restrict__ hist,
                                                  const int* __restrict__ offs,
                                                  const int* __restrict__ bsums,
                                                  const int* __restrict__ bbase,
                                                  int nbuck,
                                                  int* __restrict__ rowst,
                                                  int* __restrict__ rowend,
                                                  float* __restrict__ dinv,
                                                  int* __restrict__ col,
                                                  const float* __restrict__ x,
                                                  _Float16* __restrict__ msgX, int N) {
    __shared__ unsigned se[CAP];
    __shared__ int cj[PB], sj[PB], sb[PB];
    __shared__ int cnt_s[BNODES], scan_s[BNODES], cur_s[BNODES];
    __shared__ float di_s[BNODES];

    int b = blockIdx.x, tid = threadIdx.x;
    int node0 = b << BSHIFT;
    int nn = min(BNODES, N - node0);
    int beg = bbase[b];

    if (tid < PB) {
        long flat = (long)tid * nbuck + b;
        cj[tid] = hist[flat];
        sj[tid] = offs[flat] + bsums[flat >> 8];
    }
    if (tid < BNODES) cnt_s[tid] = 0;
    __syncthreads();

    if (tid < PB) sb[tid] = cj[tid];
    __syncthreads();
    for (int off = 1; off < PB; off <<= 1) {
        int t = 0;
        if (tid < PB && tid >= off) t = sb[tid - off];
        __syncthreads();
        if (tid < PB) sb[tid] += t;
        __syncthreads();
    }
    int m = sb[PB - 1];
    __syncthreads();

    // gather segments into LDS: 1 thread per segment (~8 edges each)
    {
        int j = tid;
        int base = sb[j] - cj[j], c = cj[j], s0 = sj[j];
        for (int k = 0; k < c; k++) {
            unsigned e = ebuf[s0 + k];
            int idx = base + k;
            if (idx < CAP) se[idx] = e;
            else atomicAdd(&cnt_s[e >> 25], 1);
        }
    }
    __syncthreads();

    int mcap = m < CAP ? m : CAP;
    for (int i = tid; i < mcap; i += 256) atomicAdd(&cnt_s[se[i] >> 25], 1);
    __syncthreads();

    int v = (tid < BNODES) ? cnt_s[tid] : 0;
    if (tid < BNODES) scan_s[tid] = v;
    __syncthreads();
    for (int off = 1; off < BNODES; off <<= 1) {
        int t = 0;
        if (tid < BNODES && tid >= off) t = scan_s[tid - off];
        __syncthreads();
        if (tid < BNODES) scan_s[tid] += t;
        __syncthreads();
    }
    if (tid < nn) {
        int ex = scan_s[tid] - v;
        int st = beg + ex;
        rowst[node0 + tid] = st;
        rowend[node0 + tid] = st + v;
        float di = rsqrtf((float)v + 1.0f);
        dinv[node0 + tid] = di;
        di_s[tid] = di;
        cur_s[tid] = ex;
    }
    __syncthreads();

    for (int i = tid; i < mcap; i += 256) {
        unsigned e = se[i];
        int p = atomicAdd(&cur_s[e >> 25], 1);
        col[beg + p] = (int)(e & 0x1FFFFFFu);
    }
    if (m > CAP) {  // overflow spill (statistically never)
        int j = tid;
        int base = sb[j] - cj[j], c = cj[j], s0 = sj[j];
        for (int k = 0; k < c; k++) {
            int idx = base + k;
            if (idx >= CAP) {
                unsigned e = ebuf[s0 + k];
                int p = atomicAdd(&cur_s[e >> 25], 1);
                col[beg + p] = (int)(e & 0x1FFFFFFu);
            }
        }
    }

    // fused msgX prep: msgX[n,64] f16 = dinv[n] * x[n,:]
    for (int t = tid; t < nn * 16; t += 256) {
        int nl = t >> 4, q = t & 15;
        int node = node0 + nl;
        float4 vx = *(const float4*)(x + (long)node * 64 + q * 4);
        float di = di_s[nl];
        vx.x *= di; vx.y *= di; vx.z *= di; vx.w *= di;
        store4h(msgX + (long)node * 64 + q * 4, vx);
    }
}

// ---- fused aggregate + MFMA GEMM ------------------------------------------
// block = 64 nodes. Phase 1: agg into LDS tile (f16, dinv-scaled).
// Phase 2: C[64,FOUT] = epi(As @ W), W B-fragments read from global (L1-hot).
template <int K, int FOUT, bool BIAS, bool RELU, bool DINV_OUT>
__global__ __launch_bounds__(256) void fag_k(const _Float16* __restrict__ msg,
                                             const int* __restrict__ rowst,
                                             const int* __restrict__ rowend,
                                             const int* __restrict__ col,
                                             const float* __restrict__ dinv,
                                             const _Float16* __restrict__ Wsw,
                                             const float* __restrict__ bias,
                                             _Float16* __restrict__ C, int n) {
    constexpr int NT = FOUT / 16, NC = K / 32;
    constexpr int LDK = K + 8;          // +16B pad: phase-2 reads 2-way only
    __shared__ _Float16 As[64 * LDK];

    int tid = threadIdx.x;
    int row0 = blockIdx.x * 64;

    // phase 1: aggregate 64 nodes into As
    constexpr int LPN = K / 8;
    constexpr int NPB = 256 / LPN;
#pragma unroll
    for (int pass = 0; pass < 64 / NPB; pass++) {
        int nl = pass * NPB + tid / LPN;
        int q = tid % LPN;
        int node = row0 + nl;
        float acc[8];
        if (node < n) {
            load8h(msg + (long)node * K + q * 8, acc);  // self (dinv folded)
            int beg = rowst[node], end = rowend[node];
            int e = beg;
            for (; e + 4 <= end; e += 4) {
                int s0 = col[e], s1 = col[e + 1], s2 = col[e + 2], s3 = col[e + 3];
                float v0[8], v1[8], v2[8], v3[8];
                load8h(msg + (long)s0 * K + q * 8, v0);
                load8h(msg + (long)s1 * K + q * 8, v1);
                load8h(msg + (long)s2 * K + q * 8, v2);
                load8h(msg + (long)s3 * K + q * 8, v3);
#pragma unroll
                for (int j = 0; j < 8; j++) acc[j] += (v0[j] + v1[j]) + (v2[j] + v3[j]);
            }
            for (; e < end; e++) {
                int s = col[e];
                float v[8];
                load8h(msg + (long)s * K + q * 8, v);
#pragma unroll
                for (int j = 0; j < 8; j++) acc[j] += v[j];
            }
            float di = dinv[node];
#pragma unroll
            for (int j = 0; j < 8; j++) acc[j] *= di;
        } else {
#pragma unroll
            for (int j = 0; j < 8; j++) acc[j] = 0.f;
        }
        h8 o;
#pragma unroll
        for (int j = 0; j < 8; j++) o[j] = (_Float16)acc[j];
        *(h8*)(As + nl * LDK + q * 8) = o;
    }
    __syncthreads();

    // phase 2: MFMA, one 16-row tile per wave
    int lane = tid & 63, wave = tid >> 6;
    int quad = lane >> 4, cl = lane & 15;
    int r0 = wave * 16;

    h8 a[NC];
#pragma unroll
    for (int c = 0; c < NC; c++)
        a[c] = *(const h8*)(As + (r0 + cl) * LDK + quad * 8 + c * 32);

    f4 acc2[NT];
#pragma unroll
    for (int t = 0; t < NT; t++) acc2[t] = (f4){0.f, 0.f, 0.f, 0.f};

    const h8* wv = (const h8*)Wsw;
#pragma unroll
    for (int c = 0; c < NC; c++) {
#pragma unroll
        for (int t = 0; t < NT; t++)
            acc2[t] = __builtin_amdgcn_mfma_f32_16x16x32_f16(
                a[c], wv[(c * NT + t) * 64 + lane], acc2[t], 0, 0, 0);
    }

    // C/D layout: col = lane&15, row = quad*4 + reg
#pragma unroll
    for (int t = 0; t < NT; t++) {
        int c0 = t * 16 + cl;
        float bb = BIAS ? bias[c0] : 0.f;
#pragma unroll
        for (int r = 0; r < 4; r++) {
            int row = row0 + r0 + quad * 4 + r;
            if (row >= n) continue;
            float v = acc2[t][r] + bb;
            if (RELU) v = fmaxf(v, 0.f);
            if (DINV_OUT) v *= dinv[row];
            C[(long)row * FOUT + c0] = (_Float16)v;
        }
    }
}

// ---- standalone aggregation (layer 3 output) ------------------------------
template <int F, bool BIAS, bool F16OUT>
__global__ __launch_bounds__(256) void agg_f16_k(const _Float16* __restrict__ msg,
                                                 const int* __restrict__ rowst,
                                                 const int* __restrict__ rowend,
                                                 const int* __restrict__ col,
                                                 const float* __restrict__ dinv,
                                                 const float* __restrict__ b,
                                                 void* __restrict__ out, int n) {
    constexpr int LPN = F / 8;
    constexpr int NPB = 256 / LPN;
    int node = blockIdx.x * NPB + threadIdx.x / LPN;
    int q = threadIdx.x % LPN;
    if (node >= n) return;

    float acc[8];
    load8h(msg + (long)node * F + q * 8, acc);

    int beg = rowst[node], end = rowend[node];
    int e = beg;
    for (; e + 4 <= end; e += 4) {
        int s0 = col[e], s1 = col[e + 1], s2 = col[e + 2], s3 = col[e + 3];
        float v0[8], v1[8], v2[8], v3[8];
        load8h(msg + (long)s0 * F + q * 8, v0);
        load8h(msg + (long)s1 * F + q * 8, v1);
        load8h(msg + (long)s2 * F + q * 8, v2);
        load8h(msg + (long)s3 * F + q * 8, v3);
#pragma unroll
        for (int j = 0; j < 8; j++) acc[j] += (v0[j] + v1[j]) + (v2[j] + v3[j]);
    }
    for (; e < end; e++) {
        int s = col[e];
        float v[8];
        load8h(msg + (long)s * F + q * 8, v);
#pragma unroll
        for (int j = 0; j < 8; j++) acc[j] += v[j];
    }

    float di = dinv[node];
    float o[8];
#pragma unroll
    for (int j = 0; j < 8; j++) o[j] = di * acc[j];
    if (BIAS) {
#pragma unroll
        for (int j = 0; j < 8; j++) o[j] += b[q * 8 + j];
    }
    if (F16OUT) {
        store8h((_Float16*)out + (long)node * F + q * 8, o);
    } else {
        float* dst = (float*)out + (long)node * F + q * 8;
        *(float4*)dst = make_float4(o[0], o[1], o[2], o[3]);
        *(float4*)(dst + 4) = make_float4(o[4], o[5], o[6], o[7]);
    }
}

// ---- MFMA dense transform (layer 3, W in LDS) -----------------------------
template <int K, int FOUT>
__device__ inline void wfrag(const float* __restrict__ W,
                             _Float16* __restrict__ Wsw, int t) {
    constexpr int NT = FOUT / 16;
    int lane = t & 63;
    int tile = (t >> 6) % NT;
    int chunk = (t >> 6) / NT;
    int kbase = chunk * 32 + (lane >> 4) * 8;
    int nc = tile * 16 + (lane & 15);
    h8 v;
#pragma unroll
    for (int j = 0; j < 8; j++) v[j] = (_Float16)W[(kbase + j) * FOUT + nc];
    ((h8*)Wsw)[t] = v;
}

// one kernel for all three weight swizzles (W1:1024, W2:2048, W3:1024 h8's)
__global__ __launch_bounds__(256) void wprep3_k(const float* __restrict__ W1,
                                                const float* __restrict__ W2,
                                                const float* __restrict__ W3,
                                                _Float16* __restrict__ w1s,
                                                _Float16* __restrict__ w2s,
                                                _Float16* __restrict__ w3s) {
    int t = blockIdx.x * 256 + threadIdx.x;
    if (t < 1024) wfrag<64, 128>(W1, w1s, t);
    else if (t < 3072) wfrag<128, 128>(W2, w2s, t - 1024);
    else if (t < 4096) wfrag<128, 64>(W3, w3s, t - 3072);
}

template <int K, int FOUT, bool BIAS, bool RELU, bool DINV>
__global__ __launch_bounds__(256) void gemm_mfma_k(const _Float16* __restrict__ A,
                                                   const _Float16* __restrict__ Wsw,
                                                   const float* __restrict__ bias,
                                                   const float* __restrict__ dinv,
                                                   _Float16* __restrict__ C, int n) {
    constexpr int NT = FOUT / 16;
    constexpr int NC = K / 32;
    __shared__ _Float16 wl[K * FOUT];

    int tid = threadIdx.x;
    for (int i = tid; i < K * FOUT / 8; i += 256)
        ((h8*)wl)[i] = ((const h8*)Wsw)[i];
    __syncthreads();

    int lane = tid & 63, wave = tid >> 6;
    int quad = lane >> 4, cl = lane & 15;
    int row0 = blockIdx.x * 64 + wave * 16;

    h8 a[NC];
    const _Float16* arow = A + (long)(row0 + cl) * K + quad * 8;
#pragma unroll
    for (int c = 0; c < NC; c++) a[c] = *(const h8*)(arow + c * 32);

    f4 acc[NT];
#pragma unroll
    for (int t = 0; t < NT; t++) acc[t] = (f4){0.f, 0.f, 0.f, 0.f};

    const h8* wv = (const h8*)wl;
#pragma unroll
    for (int c = 0; c < NC; c++) {
#pragma unroll
        for (int t = 0; t < NT; t++)
            acc[t] = __builtin_amdgcn_mfma_f32_16x16x32_f16(
                a[c], wv[(c * NT + t) * 64 + lane], acc[t], 0, 0, 0);
    }

#pragma unroll
    for (int t = 0; t < NT; t++) {
        int c0 = t * 16 + cl;
        float bb = BIAS ? bias[c0] : 0.f;
#pragma unroll
        for (int r = 0; r < 4; r++) {
            int row = row0 + quad * 4 + r;
            if (row >= n) continue;
            float v = acc[t][r] + bb;
            if (RELU) v = fmaxf(v, 0.f);
            if (DINV) v *= dinv[row];
            C[(long)row * FOUT + c0] = (_Float16)v;
        }
    }
}

extern "C" void kernel_launch(void* const* d_in, const int* in_sizes, int n_in,
                              void* d_out, int out_size, void* d_ws, size_t ws_size,
                              hipStream_t stream) {
    const float* x  = (const float*)d_in[0];
    const int*   ei = (const int*)d_in[1];
    const float* W1 = (const float*)d_in[2];
    const float* b1 = (const float*)d_in[3];
    const float* W2 = (const float*)d_in[4];
    const float* b2 = (const float*)d_in[5];
    const float* W3 = (const float*)d_in[6];
    const float* b3 = (const float*)d_in[7];
    float* out = (float*)d_out;

    const int N = in_sizes[0] / 64;
    const int E = in_sizes[1] / 2;
    const int* src = ei;
    const int* dst = ei + E;
    const int nbuck = (N + BNODES - 1) >> BSHIFT;   // 782
    const int chunk = (E + PB - 1) / PB;            // 6250
    const int n2 = PB * nbuck;                      // 200192
    const int nb2 = (n2 + 255) / 256;               // 782

    // workspace carve-up (4-byte elems)
    int*   hist   = (int*)d_ws;                   // PB*nbuck
    int*   offs   = hist + n2;                    // PB*nbuck
    int*   bsums  = offs + n2;                    // 1024
    int*   bbase  = bsums + 1024;                 // nbuck+1
    int*   rowst  = bbase + nbuck + 1;            // N
    int*   rowend = rowst + N;                    // N
    float* dinv   = (float*)(rowend + N);         // N
    int*   col    = (int*)(dinv + N);             // E
    _Float16* w1s = (_Float16*)(col + E);         // 64*128 f16
    _Float16* w2s = w1s + 64 * 128;               // 128*128 f16
    _Float16* w3s = w2s + 128 * 128;              // 128*64 f16
    float* P      = (float*)(w3s + 128 * 64);     // N*128 f32 worth
    float* Q      = P + (long)N * 128;            // N*128 f32 worth

    _Float16* msgX = (_Float16*)P;    // N x 64 f16
    unsigned* ebuf = (unsigned*)Q;    // E x 4B (dead after finalize)
    _Float16* msg1 = (_Float16*)Q;    // N x 128 f16 (F1 out; != msgX buffer!)
    _Float16* h2   = (_Float16*)P;    // N x 128 f16 (F2 out; msgX dead)
    _Float16* msg3 = (_Float16*)Q;    // N x 64 f16  (gemm3 out; msg1 dead)

    const int gb = (N + 63) / 64;

    // ---- weight swizzle (one kernel) ----
    wprep3_k<<<16, 256, 0, stream>>>(W1, W2, W3, w1s, w2s, w3s);

    // ---- CSR build ----
    phist_k<<<PB, 256, 0, stream>>>(dst, hist, E, nbuck, chunk);
    scan_blocks_k<<<nb2, 256, 0, stream>>>(hist, offs, bsums, n2);
    mid_k<<<2, 1024, 0, stream>>>(bsums, nb2, hist, bbase, nbuck, E);
    part2_k<<<PB, 256, 0, stream>>>(src, dst, offs, bsums, ebuf, E, nbuck, chunk);
    finalize_k<<<nbuck, 256, 0, stream>>>(ebuf, hist, offs, bsums, bbase, nbuck,
                                          rowst, rowend, dinv, col, x, msgX, N);

    // ---- layer 1 (fused agg+gemm): msgX(P) -> msg1(Q) ----
    fag_k<64, 128, true, true, true><<<gb, 256, 0, stream>>>(
        msgX, rowst, rowend, col, dinv, w1s, b1, msg1, N);

    // ---- layer 2 (fused agg+gemm): msg1(Q) -> h2(P) ----
    fag_k<128, 128, true, true, false><<<gb, 256, 0, stream>>>(
        msg1, rowst, rowend, col, dinv, w2s, b2, h2, N);

    // ---- layer 3: gemm h2(P) -> msg3(Q); agg -> out ----
    gemm_mfma_k<128, 64, false, false, true><<<gb, 256, 0, stream>>>(
        h2, w3s, nullptr, dinv, msg3, N);
    agg_f16_k<64, true, false><<<(N + 31) / 32, 256, 0, stream>>>(
        msg3, rowst, rowend, col, dinv, b3, (void*)out, N);
}